// Round 8
// baseline (317.573 us; speedup 1.0000x reference)
//
#include <hip/hip_runtime.h>
#include <stdint.h>

// Disable FMA contraction file-wide: we must replicate the reference's
// per-op f32 rounding (decode + IoU) to avoid NMS decision flips.
#pragma clang fp contract(off)

#define B_IMGS   4
#define NLVL     5
#define A_TOTAL  242991
#define NSEL     4741          // 1000*4 + 741
#define NBUCK    8192          // 13-bit buckets: sign+exp+4 mantissa (os>>19)
#define BSHIFT   19
#define CAND_CAP 2048
#define POST_NMS 1000
#define NBL      (B_IMGS * NLVL)
#define NMS_TH   0.7f
#define NEGV     (-1e10f)
#define W_IMGF   1216.0f
#define H_IMGF   800.0f
#define MIN_SZ   1e-3f
#define BBOX_CLIP 4.135166556742356f   // log(1000/16), rounded to f32 by compiler

#define NSLICE_PER_IMG 34      // hist slices per image (l0:24 l1:6 l2:2 l3:1 l4:1-unused)

// ---------- level helpers ----------
__device__ __forceinline__ int lvl_k(int l) { return (l == 4) ? 741 : 1000; }

// ---------- order-preserving float<->uint ----------
__device__ __forceinline__ unsigned flipf(float f) {
    unsigned u = __float_as_uint(f);
    return u ^ (unsigned)(((int)u >> 31) | 0x80000000);
}
__device__ __forceinline__ float unflipf(unsigned os) {
    unsigned u = (os & 0x80000000u) ? (os ^ 0x80000000u) : ~os;
    return __uint_as_float(u);
}

// ---------- workspace layout (NOTHING pre-zeroed; cnt+done zeroed by k_hist) ----------
static constexpr size_t OFF_BM5   = 0;                                        // u32[20]
static constexpr size_t OFF_CNT   = 128;                                      // u32[20]
static constexpr size_t OFF_DONE  = 208;                                      // u32[4]
static constexpr size_t OFF_HSL   = 256;                                      // u32[4*34*8192]
static constexpr size_t OFF_PSL   = OFF_HSL  + (size_t)B_IMGS * NSLICE_PER_IMG * NBUCK * 4;
static constexpr size_t OFF_CAND  = OFF_PSL  + (size_t)B_IMGS * NSLICE_PER_IMG * 256 * 4;
static constexpr size_t OFF_SEL   = OFF_CAND + (size_t)NBL * CAND_CAP * 8;
static constexpr size_t OFF_BOXR  = OFF_SEL  + (size_t)B_IMGS * NSEL * 8;
static constexpr size_t OFF_SCR   = OFF_BOXR + (size_t)B_IMGS * NSEL * 16;
static constexpr size_t OFF_BOXL  = OFF_SCR  + (size_t)B_IMGS * NSEL * 4;
static constexpr size_t OFF_VAL   = OFF_BOXL + (size_t)B_IMGS * NSEL * 16;
static constexpr size_t OFF_RMAP  = OFF_VAL  + (size_t)B_IMGS * NSEL * 4;
static constexpr size_t OFF_KEEP  = OFF_RMAP + (size_t)B_IMGS * NSEL * 4;
static constexpr size_t WS_NEED   = OFF_KEEP + (size_t)B_IMGS * NSEL * 4;     // ~6 MB

// ---------- K1: per-span LDS histogram -> private global slice (no atomics) ----------
// 34 blocks/image, 512 threads. l4 block zeroes cnt+done instead (n<=k for l4).
#define HBLK_PER_IMG 34
__global__ __launch_bounds__(512) void k_hist(const float* __restrict__ obj,
                                              unsigned* __restrict__ hist_sl,
                                              unsigned* __restrict__ part_sl,
                                              unsigned* __restrict__ cntz) {
    __shared__ __align__(16) unsigned lh[NBUCK];   // 32 KB
    const int tid = threadIdx.x;     // 512
    const int b = blockIdx.x / HBLK_PER_IMG;
    const int r = blockIdx.x - b * HBLK_PER_IMG;
    if (r == 33) {                   // l4 block: zero cnt[20] + done[4] once
        if (b == 0 && tid < NBL + B_IMGS) cntz[tid] = 0;
        return;
    }
    int sofs, sub, chunk, lstart, n;
    if (r < 24)      { sofs = 0;  sub = r;      chunk = 7600; lstart = 0;      n = 182400; }
    else if (r < 30) { sofs = 24; sub = r - 24; chunk = 7600; lstart = 182400; n = 45600; }
    else if (r < 32) { sofs = 30; sub = r - 30; chunk = 5700; lstart = 228000; n = 11400; }
    else             { sofs = 32; sub = 0;      chunk = 2850; lstart = 239400; n = 2850; }
    #pragma unroll
    for (int i = tid; i < NBUCK; i += 512) lh[i] = 0;
    __syncthreads();
    const int s0 = sub * chunk;
    const int m = min(chunk, n - s0);
    const float* src = obj + (size_t)b * A_TOTAL + lstart + s0;
    // vectorized histogram (float4 + 4-deep unroll; peel to 16B alignment)
    const int peel0 = (int)(((16u - ((unsigned)(uintptr_t)src & 15u)) & 15u) >> 2);
    const int peel  = (peel0 < m) ? peel0 : m;
    const int nv    = (m - peel) >> 2;
    const float4* s4 = (const float4*)(src + peel);
    const int tail0 = peel + (nv << 2);
#define H1(f) atomicAdd(&lh[flipf(f) >> BSHIFT], 1u)
#define H4(v) do { H1((v).x); H1((v).y); H1((v).z); H1((v).w); } while (0)
    if (tid < peel) H1(src[tid]);
    for (int i = tid; i < nv; i += 2048) {
        if (i + 1536 < nv) {
            float4 a0 = s4[i], a1 = s4[i + 512], a2 = s4[i + 1024], a3 = s4[i + 1536];
            H4(a0); H4(a1); H4(a2); H4(a3);
        } else {
            float4 a0 = s4[i]; H4(a0);
            if (i + 512  < nv) { float4 a = s4[i + 512];  H4(a); }
            if (i + 1024 < nv) { float4 a = s4[i + 1024]; H4(a); }
        }
    }
    for (int i = tail0 + tid; i < m; i += 512) H1(src[i]);
#undef H4
#undef H1
    __syncthreads();
    const int slice = b * NSLICE_PER_IMG + sofs + sub;
    unsigned* gh = hist_sl + (size_t)slice * NBUCK;
    #pragma unroll
    for (int i = tid; i < NBUCK / 4; i += 512)
        ((uint4*)gh)[i] = ((const uint4*)lh)[i];
    if (tid < 256) {
        unsigned s = 0;
        #pragma unroll
        for (int i = 0; i < 32; ++i) s += lh[tid * 32 + ((i + tid) & 31)];
        part_sl[(size_t)slice * 256 + tid] = s;
    }
}

// ---------- K2: threshold (from slice sums) + vectorized compact ----------
#define CBLK_PER_IMG 65
__global__ __launch_bounds__(256) void k_compact(const float* __restrict__ obj,
                                                 const unsigned* __restrict__ hist_sl,
                                                 const unsigned* __restrict__ part_sl,
                                                 unsigned* __restrict__ cnt,
                                                 unsigned long long* __restrict__ cand) {
    __shared__ unsigned long long sbuf[CAND_CAP];   // 16 KB staging
    __shared__ unsigned wsum[4];
    __shared__ unsigned fcnt[4];
    __shared__ unsigned s_cum, s_thr, lcnt, gbase;
    const int tid = threadIdx.x;     // 256
    const int b = blockIdx.x / CBLK_PER_IMG;
    const int r = blockIdx.x - b * CBLK_PER_IMG;
    int l, sofs, nsub, sub, chunk, lstart, n;
    if (r < 48)      { l = 0; sofs = 0;  nsub = 24; sub = r;      chunk = 3800; lstart = 0;      n = 182400; }
    else if (r < 60) { l = 1; sofs = 24; nsub = 6;  sub = r - 48; chunk = 3800; lstart = 182400; n = 45600; }
    else if (r < 63) { l = 2; sofs = 30; nsub = 2;  sub = r - 60; chunk = 3800; lstart = 228000; n = 11400; }
    else if (r == 63){ l = 3; sofs = 32; nsub = 1;  sub = 0;      chunk = 2850; lstart = 239400; n = 2850; }
    else             { l = 4; sofs = 33; nsub = 0;  sub = 0;      chunk = 741;  lstart = 242250; n = 741; }
    const int bl = b * NLVL + l;
    const int kl = lvl_k(l);
    if (tid == 0) { lcnt = 0; s_cum = 0; }
    __syncthreads();
    unsigned T = 0;
    if (l < 4) {   // l4: n <= k -> every element passes, T = 0
        const int lane = tid & 63, wv = tid >> 6;
        // stage 1: suffix(t) over 256 chunk-sums (t = 255 - tid)
        const unsigned* pb = part_sl + (size_t)(b * NSLICE_PER_IMG + sofs) * 256 + (255 - tid);
        unsigned x = 0;
        #pragma unroll 6
        for (int s = 0; s < nsub; ++s) x += pb[(size_t)s * 256];
        #pragma unroll
        for (int d = 1; d < 64; d <<= 1) {
            unsigned up = __shfl_up(x, d);
            if (lane >= d) x += up;
        }
        if (lane == 63) wsum[wv] = x;
        __syncthreads();
        unsigned add = 0;
        #pragma unroll
        for (int u = 0; u < 3; ++u) if (u < wv) add += wsum[u];
        const unsigned suffix = x + add;                 // suffix(255 - tid)
        unsigned long long bm = __ballot(suffix >= (unsigned)kl);
        if (lane == 0) fcnt[wv] = (unsigned)__popcll(bm);
        __syncthreads();
        const int chnk = (int)(fcnt[0] + fcnt[1] + fcnt[2] + fcnt[3]) - 1;
        if ((255 - tid) == chnk + 1) s_cum = suffix;     // 0 if chnk==255
        __syncthreads();
        // stage 2 (wave 0): largest bucket in chunk with suffix >= kl
        if (tid < 64) {
            unsigned y = 0;
            if (tid < 32) {
                const unsigned* hb = hist_sl + (size_t)(b * NSLICE_PER_IMG + sofs) * NBUCK
                                   + chnk * 32 + (31 - tid);
                #pragma unroll 6
                for (int s = 0; s < nsub; ++s) y += hb[(size_t)s * NBUCK];
            }
            #pragma unroll
            for (int d = 1; d < 32; d <<= 1) {
                unsigned up = __shfl_up(y, d);
                if (tid >= d) y += up;
            }
            unsigned suf2 = s_cum + y;                   // bucket i = 31 - tid
            unsigned long long bm2 = __ballot((tid < 32) && (suf2 >= (unsigned)kl));
            if (tid == 0) {
                int istar = (int)__popcll(bm2) - 1;
                s_thr = (unsigned)(chnk * 32 + istar);
            }
        }
        __syncthreads();
        T = s_thr;
    }
    // ---- vectorized pass filter into LDS staging ----
    const int s0 = sub * chunk;
    const int m = min(chunk, n - s0);
    const int abase = lstart + s0;
    const float* src = obj + (size_t)b * A_TOTAL + abase;
    const int peel0 = (int)(((16u - ((unsigned)(uintptr_t)src & 15u)) & 15u) >> 2);
    const int peel  = (peel0 < m) ? peel0 : m;
    const int nv    = (m - peel) >> 2;
    const float4* s4 = (const float4*)(src + peel);
    const int tail0 = peel + (nv << 2);
#define E1(f, idx) do { unsigned os_ = flipf(f); \
    if ((os_ >> BSHIFT) >= T) { \
        unsigned slot = atomicAdd(&lcnt, 1u); \
        if (slot < CAND_CAP) \
            sbuf[slot] = (((unsigned long long)(~os_)) << 32) | (unsigned)(idx); \
    } } while (0)
#define E4(v, gb) do { E1((v).x, (gb)); E1((v).y, (gb) + 1); \
                       E1((v).z, (gb) + 2); E1((v).w, (gb) + 3); } while (0)
    if (tid < peel) E1(src[tid], abase + tid);
    for (int i = tid; i < nv; i += 512) {
        const int gb0 = abase + peel + (i << 2);
        if (i + 256 < nv) {
            float4 a0 = s4[i], a1 = s4[i + 256];
            E4(a0, gb0);
            E4(a1, gb0 + 1024);
        } else {
            float4 a0 = s4[i];
            E4(a0, gb0);
        }
    }
    for (int i = tail0 + tid; i < m; i += 256) E1(src[i], abase + i);
#undef E4
#undef E1
    __syncthreads();
    unsigned total = lcnt; if (total > CAND_CAP) total = CAND_CAP;
    if (tid == 0) gbase = atomicAdd(&cnt[bl], total);
    __syncthreads();
    const unsigned gb = gbase;
    for (unsigned i = tid; i < total; i += 256) {
        unsigned g = gb + i;
        if (g < CAND_CAP)
            cand[(size_t)bl * CAND_CAP + g] = sbuf[i];
    }
}

// ---------- K3: per-(b,level) bitonic sort of candidates; keep top-k ----------
__global__ __launch_bounds__(1024) void k_sort(const unsigned long long* __restrict__ cand,
                                               const unsigned* __restrict__ cnt,
                                               unsigned long long* __restrict__ sel) {
    __shared__ unsigned long long keys[CAND_CAP];
    const int bl = blockIdx.x;
    const int b = bl / NLVL, l = bl - (bl / NLVL) * NLVL;
    const int tid = threadIdx.x;     // 1024
    int m = (int)cnt[bl];
    if (m > CAND_CAP) m = CAND_CAP;
    for (int i = tid; i < CAND_CAP; i += 1024)
        keys[i] = (i < m) ? cand[(size_t)bl * CAND_CAP + i] : ~0ULL;
    __syncthreads();
    for (int k = 2; k <= CAND_CAP; k <<= 1) {
        for (int j = k >> 1; j > 0; j >>= 1) {
            int i = ((tid / j) * (j << 1)) + (tid % j);
            int p = i + j;
            bool up = ((i & k) == 0);
            unsigned long long a = keys[i], c = keys[p];
            if ((a > c) == up) { keys[i] = c; keys[p] = a; }
            __syncthreads();
        }
    }
    int kl = lvl_k(l);
    for (int q = tid; q < kl; q += 1024)
        sel[(size_t)b * NSEL + l * 1000 + q] = keys[q];
}

// ---------- binary search in LDS: #elements < key ----------
__device__ __forceinline__ int lbound_lds(const unsigned long long* s, int len,
                                          unsigned long long key) {
    int lo = 0, hi = len;
    while (lo < hi) {
        int mid = (lo + hi) >> 1;
        if (s[mid] < key) lo = mid + 1; else hi = mid;
    }
    return lo;
}

// ---------- K4: decode+clip+valid; global rank via LDS 5-way merge-rank ----------
__global__ void k_decode(const float* __restrict__ deltas, const float* __restrict__ anchors,
                         const unsigned long long* __restrict__ sel,
                         float* __restrict__ boxes_r, float* __restrict__ score_r,
                         float* __restrict__ boxes_l, int* __restrict__ valid_l,
                         int* __restrict__ rankmap, unsigned* __restrict__ boxmax5) {
    __shared__ unsigned long long skey[NSEL];     // 37,928 B
    __shared__ float wmax[16];
    const int b = blockIdx.y;
    const int tid = threadIdx.x;                  // 1024
    for (int i = tid; i < NSEL; i += 1024)
        skey[i] = sel[(size_t)b * NSEL + i];
    __syncthreads();

    int p = blockIdx.x * 1024 + tid;
    bool on = p < NSEL;
    float mx = 0.0f;
    if (on) {
        int l = p / 1000;           // p in [4000,4741) -> 4
        int q = p - l * 1000;
        unsigned long long key = skey[p];
        unsigned a = (unsigned)(key & 0xFFFFFFFFu);
        unsigned os = ~((unsigned)(key >> 32));
        if (a >= A_TOTAL) a = 0;    // impossible-path safety (MAX padding)
        float score = unflipf(os);
        int r = q;
        for (int l2 = 0; l2 < NLVL; ++l2) {
            if (l2 == l) continue;
            r += lbound_lds(skey + l2 * 1000, lvl_k(l2), key);
        }
        const float* dv = deltas + ((size_t)b * A_TOTAL + a) * 4;
        const float* av = anchors + (size_t)a * 4;
        float ax1 = av[0], ay1 = av[1], ax2 = av[2], ay2 = av[3];
        float wa = ax2 - ax1, ha = ay2 - ay1;
        float cxa = ax1 + 0.5f * wa, cya = ay1 + 0.5f * ha;
        float dx = dv[0], dy = dv[1];
        float dw = fminf(dv[2], BBOX_CLIP), dh = fminf(dv[3], BBOX_CLIP);
        float cx = dx * wa + cxa, cy = dy * ha + cya;
        float w = expf(dw) * wa, h = expf(dh) * ha;
        float x1 = cx - 0.5f * w, y1 = cy - 0.5f * h;
        float x2 = cx + 0.5f * w, y2 = cy + 0.5f * h;
        float x1c = fminf(fmaxf(x1, 0.0f), W_IMGF);
        float y1c = fminf(fmaxf(y1, 0.0f), H_IMGF);
        float x2c = fminf(fmaxf(x2, 0.0f), W_IMGF);
        float y2c = fminf(fmaxf(y2, 0.0f), H_IMGF);
        int valid = ((x2c - x1c) >= MIN_SZ) && ((y2c - y1c) >= MIN_SZ);
        mx = fmaxf(fmaxf(x1c, y1c), fmaxf(x2c, y2c));
        size_t rp = (size_t)b * NSEL + r;
        boxes_r[rp * 4 + 0] = x1c; boxes_r[rp * 4 + 1] = y1c;
        boxes_r[rp * 4 + 2] = x2c; boxes_r[rp * 4 + 3] = y2c;
        score_r[rp] = score;
        size_t pp = (size_t)b * NSEL + p;
        boxes_l[pp * 4 + 0] = x1c; boxes_l[pp * 4 + 1] = y1c;
        boxes_l[pp * 4 + 2] = x2c; boxes_l[pp * 4 + 3] = y2c;
        valid_l[pp] = valid;
        rankmap[pp] = r;
    }
    #pragma unroll
    for (int o = 32; o > 0; o >>= 1)
        mx = fmaxf(mx, __shfl_xor(mx, o));
    if ((tid & 63) == 0) wmax[tid >> 6] = mx;
    __syncthreads();
    if (tid == 0) {
        float m2 = wmax[0];
        #pragma unroll
        for (int i = 1; i < 16; ++i) m2 = fmaxf(m2, wmax[i]);
        boxmax5[b * 5 + blockIdx.x] = __float_as_uint(m2);
    }
}

// ---------- EF tile: one 64-row x 16-window mask tile into LDS ----------
// Called by waves 1..15; wave q covers windows {q-1, q+14} (only w >= cc used).
// Float op order identical to the verified k_mask (R2-verified structure).
__device__ __forceinline__ void ef_tile(const float (*boxes5)[5],
                                        unsigned long long* buf,
                                        int cc, int kl, int wave, int lane) {
    const int rbase = cc << 6;
    const int i = rbase + lane;
    float ix1 = 0.f, iy1 = 0.f, ix2 = 0.f, iy2 = 0.f, ai = 0.f;
    const bool row_on = (i < kl);
    if (row_on) {
        ix1 = boxes5[i][0]; iy1 = boxes5[i][1];
        ix2 = boxes5[i][2]; iy2 = boxes5[i][3]; ai = boxes5[i][4];
    }
    for (int w = wave - 1; w < 16; w += 15) {
        if (w < cc) continue;
        const int j0 = w << 6;
        const int jmax = min(64, kl - j0);
        unsigned long long word = 0;
        if (row_on && jmax > 0) {
            for (int bb = 0; bb < jmax; ++bb) {
                int jj = j0 + bb;
                if (jj <= i) continue;
                float ltx = fmaxf(ix1, boxes5[jj][0]), lty = fmaxf(iy1, boxes5[jj][1]);
                float rbx = fminf(ix2, boxes5[jj][2]), rby = fminf(iy2, boxes5[jj][3]);
                float ww = fmaxf(rbx - ltx, 0.0f), hh = fmaxf(rby - lty, 0.0f);
                float inter = ww * hh;
                float iou = inter / ((ai + boxes5[jj][4]) - inter);  // NaN>th == false
                if (iou > NMS_TH) word |= (1ULL << bb);
            }
        }
        buf[(lane << 4) + w] = word;
    }
}

// ---------- K5: fused mask(waves 1..15, LDS tiles) || resolve(wave 0) + output ----------
// One block per (b,level): R2-verified producer-consumer pipeline — waves 1..15
// compute chunk c+1's mask tile while wave 0 greedily resolves chunk c. Keep
// bits -> keep_r (global-rank order). Last-finishing block of each image runs
// the verified k_output body (agent-scope done counter + fences, R1/R2 gbar
// pattern). Mask never touches global memory.
__global__ __launch_bounds__(1024) void k_mr(const float* __restrict__ boxes_l,
                                             const unsigned* __restrict__ boxmax5,
                                             const int* __restrict__ valid_l,
                                             const int* __restrict__ rankmap,
                                             int* __restrict__ keep_r,
                                             unsigned* __restrict__ done,
                                             const float* __restrict__ boxes_r,
                                             const float* __restrict__ score_r,
                                             float* __restrict__ out) {
    __shared__ float boxes5[1024][5];                       // 20,480 B
    __shared__ unsigned long long tileA[64 * 16];           // 8,192 B
    __shared__ unsigned long long tileB[64 * 16];           // 8,192 B
    __shared__ int ps[1024];                                // 4,096 B (epilogue)
    __shared__ int s_last;
    const int bl = blockIdx.x;
    const int b = bl / NLVL, l = bl - b * NLVL;
    const int kl = lvl_k(l);
    const int tid = threadIdx.x;     // 1024
    const int lane = tid & 63;
    const int wave = tid >> 6;
    const int base = b * NSEL + l * 1000;
    const int nch = (kl + 63) >> 6;  // 16 or 12

    float M = __uint_as_float(boxmax5[b * 5 + 0]);
    #pragma unroll
    for (int j = 1; j < 5; ++j) M = fmaxf(M, __uint_as_float(boxmax5[b * 5 + j]));
    M += 1.0f;
    const float off = (float)l * M;

    // stage all level boxes (offset-added) + areas into LDS
    if (tid < kl) {
        const float* bp = boxes_l + ((size_t)base + tid) * 4;
        float x1 = bp[0] + off, y1 = bp[1] + off;
        float x2 = bp[2] + off, y2 = bp[3] + off;
        boxes5[tid][0] = x1; boxes5[tid][1] = y1;
        boxes5[tid][2] = x2; boxes5[tid][3] = y2;
        boxes5[tid][4] = (x2 - x1) * (y2 - y1);
    } else {
        boxes5[tid][0] = 0.f; boxes5[tid][1] = 0.f;
        boxes5[tid][2] = 0.f; boxes5[tid][3] = 0.f; boxes5[tid][4] = 0.f;
    }
    unsigned long long keep_w = 0;
    __syncthreads();

    // prologue: wave0 gathers keep bits; waves 1..15 compute tile 0
    if (wave == 0) {
        for (int c2 = 0; c2 < 16; ++c2) {
            int q = (c2 << 6) + lane;
            int vv = (q < kl) ? valid_l[base + q] : 0;
            unsigned long long bm = __ballot(vv);
            if (lane == c2) keep_w = bm;
        }
    } else {
        ef_tile(boxes5, tileA, 0, kl, wave, lane);
    }
    __syncthreads();

    for (int c = 0; c < nch; ++c) {
        unsigned long long* cur = (c & 1) ? tileB : tileA;
        unsigned long long* nxt = (c & 1) ? tileA : tileB;
        if (wave > 0) {
            if (c + 1 < nch) ef_tile(boxes5, nxt, c + 1, kl, wave, lane);
        } else {
            unsigned long long kw = __shfl(keep_w, c);   // uniform in wave
            if (kw) {
                // within-chunk greedy closure (serial over nonzero-diag rows)
                unsigned long long diag = cur[(lane << 4) + c];
                unsigned dlo = (unsigned)diag, dhi = (unsigned)(diag >> 32);
                unsigned long long nz = __ballot(diag != 0ULL);
                unsigned long long rem = kw & nz;
                while (rem) {
                    int rr = __ffsll((long long)rem) - 1;
                    unsigned lo = __builtin_amdgcn_readlane(dlo, rr);
                    unsigned hi = __builtin_amdgcn_readlane(dhi, rr);
                    unsigned long long d = ((unsigned long long)hi << 32) | lo;
                    kw &= ~d;
                    rem &= ~(d | (1ULL << rr));
                }
                // batched cross-chunk suppression: lane w<16 ORs word w of kept rows
                unsigned long long supp = 0;
                if (lane < 16) {
                    #pragma unroll
                    for (int rr = 0; rr < 64; ++rr) {
                        unsigned long long mm = cur[(rr << 4) + lane];
                        supp |= (((kw >> rr) & 1ULL) ? mm : 0ULL);
                    }
                }
                if (lane == c) keep_w = kw;
                else if (lane < 16 && lane > c) keep_w &= ~supp;
            }
        }
        __syncthreads();
    }
    // scatter keep bits to global-rank order
    if (wave == 0) {
        for (int c2 = 0; c2 < 16; ++c2) {
            unsigned long long kwc = __shfl(keep_w, c2);
            int q = (c2 << 6) + lane;
            if (q < kl)
                keep_r[b * NSEL + rankmap[base + q]] = (int)((kwc >> lane) & 1ULL);
        }
    }
    __syncthreads();   // drains wave0's keep_r stores (vmcnt) before release

    // ---- last-block-per-image output epilogue ----
    if (tid == 0) {
        __threadfence();   // agent release: keep_r visible across XCDs
        unsigned old = __hip_atomic_fetch_add(done + b, 1u,
                                              __ATOMIC_ACQ_REL, __HIP_MEMORY_SCOPE_AGENT);
        s_last = (old == NLVL - 1);
        if (old == NLVL - 1) __threadfence();   // agent acquire
    }
    __syncthreads();
    if (!s_last) return;

    // verified k_output body (keep flags from global keep_r)
    float* ob = out + (size_t)b * POST_NMS * 4;
    float* osc = out + (size_t)B_IMGS * POST_NMS * 4 + (size_t)b * POST_NMS;
    for (int p = tid; p < POST_NMS; p += 1024) {
        ob[p * 4 + 0] = 0.0f; ob[p * 4 + 1] = 0.0f;
        ob[p * 4 + 2] = 0.0f; ob[p * 4 + 3] = 0.0f;
        osc[p] = NEGV;
    }
    __syncthreads();
    const int CH = 5;  // 5*1024 = 5120 >= 4741
    int basei = tid * CH;
    int c0 = 0;
    #pragma unroll
    for (int k = 0; k < CH; ++k) {
        int rr = basei + k;
        if (rr < NSEL) c0 += keep_r[b * NSEL + rr];
    }
    ps[tid] = c0;
    __syncthreads();
    for (int ofs = 1; ofs < 1024; ofs <<= 1) {
        int v = (tid >= ofs) ? ps[tid - ofs] : 0;
        __syncthreads();
        ps[tid] += v;
        __syncthreads();
    }
    int p = ps[tid] - c0;   // exclusive prefix
    #pragma unroll
    for (int k = 0; k < CH; ++k) {
        int rr = basei + k;
        if (rr < NSEL && keep_r[b * NSEL + rr]) {
            if (p < POST_NMS) {
                const float* bp = boxes_r + ((size_t)b * NSEL + rr) * 4;
                ob[p * 4 + 0] = bp[0]; ob[p * 4 + 1] = bp[1];
                ob[p * 4 + 2] = bp[2]; ob[p * 4 + 3] = bp[3];
                osc[p] = score_r[(size_t)b * NSEL + rr];
            }
            ++p;
        }
    }
}

extern "C" void kernel_launch(void* const* d_in, const int* in_sizes, int n_in,
                              void* d_out, int out_size, void* d_ws, size_t ws_size,
                              hipStream_t stream) {
    const float* obj     = (const float*)d_in[0];   // [4, 242991]
    const float* deltas  = (const float*)d_in[1];   // [4, 242991, 4]
    const float* anchors = (const float*)d_in[2];   // [242991, 4]
    float* out = (float*)d_out;                     // [4,1000,4] ++ [4,1000]

    char* ws = (char*)d_ws;
    unsigned*            boxmax5 = (unsigned*)(ws + OFF_BM5);
    unsigned*            cnt     = (unsigned*)(ws + OFF_CNT);
    unsigned*            done    = (unsigned*)(ws + OFF_DONE);
    unsigned*            hist_sl = (unsigned*)(ws + OFF_HSL);
    unsigned*            part_sl = (unsigned*)(ws + OFF_PSL);
    unsigned long long*  cand    = (unsigned long long*)(ws + OFF_CAND);
    unsigned long long*  sel     = (unsigned long long*)(ws + OFF_SEL);
    float*               boxes_r = (float*)(ws + OFF_BOXR);
    float*               score_r = (float*)(ws + OFF_SCR);
    float*               boxes_l = (float*)(ws + OFF_BOXL);
    int*                 valid_l = (int*)(ws + OFF_VAL);
    int*                 rankmap = (int*)(ws + OFF_RMAP);
    int*                 keep_r  = (int*)(ws + OFF_KEEP);

    (void)in_sizes; (void)n_in; (void)out_size; (void)ws_size; (void)WS_NEED;

    // No memset: hist/part slices are plain-store overwritten; cnt+done are
    // zeroed by k_hist's l4 block (kernel-boundary visibility); boxmax5 is
    // plain-stored by k_decode; keep_r fully written by k_mr before reads.
    k_hist<<<B_IMGS * HBLK_PER_IMG, 512, 0, stream>>>(obj, hist_sl, part_sl, cnt);
    k_compact<<<B_IMGS * CBLK_PER_IMG, 256, 0, stream>>>(obj, hist_sl, part_sl, cnt, cand);
    k_sort<<<NBL, 1024, 0, stream>>>(cand, cnt, sel);
    k_decode<<<dim3(5, B_IMGS), 1024, 0, stream>>>(
        deltas, anchors, sel, boxes_r, score_r, boxes_l, valid_l, rankmap, boxmax5);
    k_mr<<<NBL, 1024, 0, stream>>>(boxes_l, boxmax5, valid_l, rankmap,
                                   keep_r, done, boxes_r, score_r, out);
}

// Round 9
// 240.868 us; speedup vs baseline: 1.3185x; 1.3185x over previous
//
#include <hip/hip_runtime.h>
#include <stdint.h>

// Disable FMA contraction file-wide: we must replicate the reference's
// per-op f32 rounding (decode + IoU) to avoid NMS decision flips.
#pragma clang fp contract(off)

#define B_IMGS   4
#define NLVL     5
#define A_TOTAL  242991
#define NSEL     4741          // 1000*4 + 741
#define NBUCK    8192          // 13-bit buckets: sign+exp+4 mantissa (os>>19)
#define BSHIFT   19
#define CAND_CAP 2048
#define POST_NMS 1000
#define NBL      (B_IMGS * NLVL)
#define NMS_TH   0.7f
#define NEGV     (-1e10f)
#define W_IMGF   1216.0f
#define H_IMGF   800.0f
#define MIN_SZ   1e-3f
#define BBOX_CLIP 4.135166556742356f   // log(1000/16), rounded to f32 by compiler

#define NSLICE_PER_IMG 34      // hist slices per image (l0:24 l1:6 l2:2 l3:1 l4:1-unused)

// ---------- level helpers ----------
__device__ __forceinline__ int lvl_k(int l) { return (l == 4) ? 741 : 1000; }

// ---------- order-preserving float<->uint ----------
__device__ __forceinline__ unsigned flipf(float f) {
    unsigned u = __float_as_uint(f);
    return u ^ (unsigned)(((int)u >> 31) | 0x80000000);
}
__device__ __forceinline__ float unflipf(unsigned os) {
    unsigned u = (os & 0x80000000u) ? (os ^ 0x80000000u) : ~os;
    return __uint_as_float(u);
}

// ---------- async global->LDS DMA (16B per lane, wave-uniform LDS base) ----------
__device__ __forceinline__ void async_cp16(const void* g, void* l) {
    __builtin_amdgcn_global_load_lds(
        (const __attribute__((address_space(1))) unsigned*)g,
        (__attribute__((address_space(3))) unsigned*)l,
        16, 0, 0);
}

// ---------- workspace layout (NOTHING pre-zeroed; cnt/done zeroed by k_hist) ----------
static constexpr size_t OFF_BM5   = 0;                                        // u32[20]
static constexpr size_t OFF_CNT   = 128;                                      // u32[20]
static constexpr size_t OFF_DONE1 = 208;                                      // u32[20]
static constexpr size_t OFF_DONE2 = 288;                                      // u32[4]
static constexpr size_t OFF_HSL   = 320;                                      // u32[4*34*8192]
static constexpr size_t OFF_PSL   = OFF_HSL  + (size_t)B_IMGS * NSLICE_PER_IMG * NBUCK * 4;
static constexpr size_t OFF_CAND  = OFF_PSL  + (size_t)B_IMGS * NSLICE_PER_IMG * 256 * 4;
static constexpr size_t OFF_SEL   = OFF_CAND + (size_t)NBL * CAND_CAP * 8;
static constexpr size_t OFF_BOXR  = OFF_SEL  + (size_t)B_IMGS * NSEL * 8;
static constexpr size_t OFF_SCR   = OFF_BOXR + (size_t)B_IMGS * NSEL * 16;
static constexpr size_t OFF_BOXL  = OFF_SCR  + (size_t)B_IMGS * NSEL * 4;
static constexpr size_t OFF_VAL   = OFF_BOXL + (size_t)B_IMGS * NSEL * 16;
static constexpr size_t OFF_RMAP  = OFF_VAL  + (size_t)B_IMGS * NSEL * 4;
static constexpr size_t OFF_KEEP  = OFF_RMAP + (size_t)B_IMGS * NSEL * 4;
static constexpr size_t OFF_MASK  = (OFF_KEEP + (size_t)B_IMGS * NSEL * 4 + 15) & ~(size_t)15;
static constexpr size_t WS_NEED   = OFF_MASK + (size_t)NBL * 1024 * 16 * 8;   // ~8.5 MB

// ---------- K1: per-span LDS histogram -> private global slice (no atomics) ----------
// 34 blocks/image, 512 threads. l4 block zeroes cnt+done1+done2 instead.
#define HBLK_PER_IMG 34
__global__ __launch_bounds__(512) void k_hist(const float* __restrict__ obj,
                                              unsigned* __restrict__ hist_sl,
                                              unsigned* __restrict__ part_sl,
                                              unsigned* __restrict__ cntz) {
    __shared__ __align__(16) unsigned lh[NBUCK];   // 32 KB
    const int tid = threadIdx.x;     // 512
    const int b = blockIdx.x / HBLK_PER_IMG;
    const int r = blockIdx.x - b * HBLK_PER_IMG;
    if (r == 33) {                   // l4 block: zero cnt[20]+done1[20]+done2[4]
        if (b == 0 && tid < NBL + NBL + B_IMGS) cntz[tid] = 0;
        return;
    }
    int sofs, sub, chunk, lstart, n;
    if (r < 24)      { sofs = 0;  sub = r;      chunk = 7600; lstart = 0;      n = 182400; }
    else if (r < 30) { sofs = 24; sub = r - 24; chunk = 7600; lstart = 182400; n = 45600; }
    else if (r < 32) { sofs = 30; sub = r - 30; chunk = 5700; lstart = 228000; n = 11400; }
    else             { sofs = 32; sub = 0;      chunk = 2850; lstart = 239400; n = 2850; }
    #pragma unroll
    for (int i = tid; i < NBUCK; i += 512) lh[i] = 0;
    __syncthreads();
    const int s0 = sub * chunk;
    const int m = min(chunk, n - s0);
    const float* src = obj + (size_t)b * A_TOTAL + lstart + s0;
    // vectorized histogram (float4 + 4-deep unroll; peel to 16B alignment)
    const int peel0 = (int)(((16u - ((unsigned)(uintptr_t)src & 15u)) & 15u) >> 2);
    const int peel  = (peel0 < m) ? peel0 : m;
    const int nv    = (m - peel) >> 2;
    const float4* s4 = (const float4*)(src + peel);
    const int tail0 = peel + (nv << 2);
#define H1(f) atomicAdd(&lh[flipf(f) >> BSHIFT], 1u)
#define H4(v) do { H1((v).x); H1((v).y); H1((v).z); H1((v).w); } while (0)
    if (tid < peel) H1(src[tid]);
    for (int i = tid; i < nv; i += 2048) {
        if (i + 1536 < nv) {
            float4 a0 = s4[i], a1 = s4[i + 512], a2 = s4[i + 1024], a3 = s4[i + 1536];
            H4(a0); H4(a1); H4(a2); H4(a3);
        } else {
            float4 a0 = s4[i]; H4(a0);
            if (i + 512  < nv) { float4 a = s4[i + 512];  H4(a); }
            if (i + 1024 < nv) { float4 a = s4[i + 1024]; H4(a); }
        }
    }
    for (int i = tail0 + tid; i < m; i += 512) H1(src[i]);
#undef H4
#undef H1
    __syncthreads();
    const int slice = b * NSLICE_PER_IMG + sofs + sub;
    unsigned* gh = hist_sl + (size_t)slice * NBUCK;
    #pragma unroll
    for (int i = tid; i < NBUCK / 4; i += 512)
        ((uint4*)gh)[i] = ((const uint4*)lh)[i];
    if (tid < 256) {
        unsigned s = 0;
        #pragma unroll
        for (int i = 0; i < 32; ++i) s += lh[tid * 32 + ((i + tid) & 31)];
        part_sl[(size_t)slice * 256 + tid] = s;
    }
}

// ---------- K2: threshold (from slice sums) + vectorized compact ----------
#define CBLK_PER_IMG 65
__global__ __launch_bounds__(256) void k_compact(const float* __restrict__ obj,
                                                 const unsigned* __restrict__ hist_sl,
                                                 const unsigned* __restrict__ part_sl,
                                                 unsigned* __restrict__ cnt,
                                                 unsigned long long* __restrict__ cand) {
    __shared__ unsigned long long sbuf[CAND_CAP];   // 16 KB staging
    __shared__ unsigned wsum[4];
    __shared__ unsigned fcnt[4];
    __shared__ unsigned s_cum, s_thr, lcnt, gbase;
    const int tid = threadIdx.x;     // 256
    const int b = blockIdx.x / CBLK_PER_IMG;
    const int r = blockIdx.x - b * CBLK_PER_IMG;
    int l, sofs, nsub, sub, chunk, lstart, n;
    if (r < 48)      { l = 0; sofs = 0;  nsub = 24; sub = r;      chunk = 3800; lstart = 0;      n = 182400; }
    else if (r < 60) { l = 1; sofs = 24; nsub = 6;  sub = r - 48; chunk = 3800; lstart = 182400; n = 45600; }
    else if (r < 63) { l = 2; sofs = 30; nsub = 2;  sub = r - 60; chunk = 3800; lstart = 228000; n = 11400; }
    else if (r == 63){ l = 3; sofs = 32; nsub = 1;  sub = 0;      chunk = 2850; lstart = 239400; n = 2850; }
    else             { l = 4; sofs = 33; nsub = 0;  sub = 0;      chunk = 741;  lstart = 242250; n = 741; }
    const int bl = b * NLVL + l;
    const int kl = lvl_k(l);
    if (tid == 0) { lcnt = 0; s_cum = 0; }
    __syncthreads();
    unsigned T = 0;
    if (l < 4) {   // l4: n <= k -> every element passes, T = 0
        const int lane = tid & 63, wv = tid >> 6;
        // stage 1: suffix(t) over 256 chunk-sums (t = 255 - tid)
        const unsigned* pb = part_sl + (size_t)(b * NSLICE_PER_IMG + sofs) * 256 + (255 - tid);
        unsigned x = 0;
        #pragma unroll 6
        for (int s = 0; s < nsub; ++s) x += pb[(size_t)s * 256];
        #pragma unroll
        for (int d = 1; d < 64; d <<= 1) {
            unsigned up = __shfl_up(x, d);
            if (lane >= d) x += up;
        }
        if (lane == 63) wsum[wv] = x;
        __syncthreads();
        unsigned add = 0;
        #pragma unroll
        for (int u = 0; u < 3; ++u) if (u < wv) add += wsum[u];
        const unsigned suffix = x + add;                 // suffix(255 - tid)
        unsigned long long bm = __ballot(suffix >= (unsigned)kl);
        if (lane == 0) fcnt[wv] = (unsigned)__popcll(bm);
        __syncthreads();
        const int chnk = (int)(fcnt[0] + fcnt[1] + fcnt[2] + fcnt[3]) - 1;
        if ((255 - tid) == chnk + 1) s_cum = suffix;     // 0 if chnk==255
        __syncthreads();
        // stage 2 (wave 0): largest bucket in chunk with suffix >= kl
        if (tid < 64) {
            unsigned y = 0;
            if (tid < 32) {
                const unsigned* hb = hist_sl + (size_t)(b * NSLICE_PER_IMG + sofs) * NBUCK
                                   + chnk * 32 + (31 - tid);
                #pragma unroll 6
                for (int s = 0; s < nsub; ++s) y += hb[(size_t)s * NBUCK];
            }
            #pragma unroll
            for (int d = 1; d < 32; d <<= 1) {
                unsigned up = __shfl_up(y, d);
                if (tid >= d) y += up;
            }
            unsigned suf2 = s_cum + y;                   // bucket i = 31 - tid
            unsigned long long bm2 = __ballot((tid < 32) && (suf2 >= (unsigned)kl));
            if (tid == 0) {
                int istar = (int)__popcll(bm2) - 1;
                s_thr = (unsigned)(chnk * 32 + istar);
            }
        }
        __syncthreads();
        T = s_thr;
    }
    // ---- vectorized pass filter into LDS staging ----
    const int s0 = sub * chunk;
    const int m = min(chunk, n - s0);
    const int abase = lstart + s0;
    const float* src = obj + (size_t)b * A_TOTAL + abase;
    const int peel0 = (int)(((16u - ((unsigned)(uintptr_t)src & 15u)) & 15u) >> 2);
    const int peel  = (peel0 < m) ? peel0 : m;
    const int nv    = (m - peel) >> 2;
    const float4* s4 = (const float4*)(src + peel);
    const int tail0 = peel + (nv << 2);
#define E1(f, idx) do { unsigned os_ = flipf(f); \
    if ((os_ >> BSHIFT) >= T) { \
        unsigned slot = atomicAdd(&lcnt, 1u); \
        if (slot < CAND_CAP) \
            sbuf[slot] = (((unsigned long long)(~os_)) << 32) | (unsigned)(idx); \
    } } while (0)
#define E4(v, gb) do { E1((v).x, (gb)); E1((v).y, (gb) + 1); \
                       E1((v).z, (gb) + 2); E1((v).w, (gb) + 3); } while (0)
    if (tid < peel) E1(src[tid], abase + tid);
    for (int i = tid; i < nv; i += 512) {
        const int gb0 = abase + peel + (i << 2);
        if (i + 256 < nv) {
            float4 a0 = s4[i], a1 = s4[i + 256];
            E4(a0, gb0);
            E4(a1, gb0 + 1024);
        } else {
            float4 a0 = s4[i];
            E4(a0, gb0);
        }
    }
    for (int i = tail0 + tid; i < m; i += 256) E1(src[i], abase + i);
#undef E4
#undef E1
    __syncthreads();
    unsigned total = lcnt; if (total > CAND_CAP) total = CAND_CAP;
    if (tid == 0) gbase = atomicAdd(&cnt[bl], total);
    __syncthreads();
    const unsigned gb = gbase;
    for (unsigned i = tid; i < total; i += 256) {
        unsigned g = gb + i;
        if (g < CAND_CAP)
            cand[(size_t)bl * CAND_CAP + g] = sbuf[i];
    }
}

// ---------- K3: per-(b,level) bitonic sort of candidates; keep top-k ----------
__global__ __launch_bounds__(1024) void k_sort(const unsigned long long* __restrict__ cand,
                                               const unsigned* __restrict__ cnt,
                                               unsigned long long* __restrict__ sel) {
    __shared__ unsigned long long keys[CAND_CAP];
    const int bl = blockIdx.x;
    const int b = bl / NLVL, l = bl - (bl / NLVL) * NLVL;
    const int tid = threadIdx.x;     // 1024
    int m = (int)cnt[bl];
    if (m > CAND_CAP) m = CAND_CAP;
    for (int i = tid; i < CAND_CAP; i += 1024)
        keys[i] = (i < m) ? cand[(size_t)bl * CAND_CAP + i] : ~0ULL;
    __syncthreads();
    for (int k = 2; k <= CAND_CAP; k <<= 1) {
        for (int j = k >> 1; j > 0; j >>= 1) {
            int i = ((tid / j) * (j << 1)) + (tid % j);
            int p = i + j;
            bool up = ((i & k) == 0);
            unsigned long long a = keys[i], c = keys[p];
            if ((a > c) == up) { keys[i] = c; keys[p] = a; }
            __syncthreads();
        }
    }
    int kl = lvl_k(l);
    for (int q = tid; q < kl; q += 1024)
        sel[(size_t)b * NSEL + l * 1000 + q] = keys[q];
}

// ---------- binary search in LDS: #elements < key ----------
__device__ __forceinline__ int lbound_lds(const unsigned long long* s, int len,
                                          unsigned long long key) {
    int lo = 0, hi = len;
    while (lo < hi) {
        int mid = (lo + hi) >> 1;
        if (s[mid] < key) lo = mid + 1; else hi = mid;
    }
    return lo;
}

// ---------- K4: decode+clip+valid; global rank via LDS 5-way merge-rank ----------
__global__ void k_decode(const float* __restrict__ deltas, const float* __restrict__ anchors,
                         const unsigned long long* __restrict__ sel,
                         float* __restrict__ boxes_r, float* __restrict__ score_r,
                         float* __restrict__ boxes_l, int* __restrict__ valid_l,
                         int* __restrict__ rankmap, unsigned* __restrict__ boxmax5) {
    __shared__ unsigned long long skey[NSEL];     // 37,928 B
    __shared__ float wmax[16];
    const int b = blockIdx.y;
    const int tid = threadIdx.x;                  // 1024
    for (int i = tid; i < NSEL; i += 1024)
        skey[i] = sel[(size_t)b * NSEL + i];
    __syncthreads();

    int p = blockIdx.x * 1024 + tid;
    bool on = p < NSEL;
    float mx = 0.0f;
    if (on) {
        int l = p / 1000;           // p in [4000,4741) -> 4
        int q = p - l * 1000;
        unsigned long long key = skey[p];
        unsigned a = (unsigned)(key & 0xFFFFFFFFu);
        unsigned os = ~((unsigned)(key >> 32));
        if (a >= A_TOTAL) a = 0;    // impossible-path safety (MAX padding)
        float score = unflipf(os);
        int r = q;
        for (int l2 = 0; l2 < NLVL; ++l2) {
            if (l2 == l) continue;
            r += lbound_lds(skey + l2 * 1000, lvl_k(l2), key);
        }
        const float* dv = deltas + ((size_t)b * A_TOTAL + a) * 4;
        const float* av = anchors + (size_t)a * 4;
        float ax1 = av[0], ay1 = av[1], ax2 = av[2], ay2 = av[3];
        float wa = ax2 - ax1, ha = ay2 - ay1;
        float cxa = ax1 + 0.5f * wa, cya = ay1 + 0.5f * ha;
        float dx = dv[0], dy = dv[1];
        float dw = fminf(dv[2], BBOX_CLIP), dh = fminf(dv[3], BBOX_CLIP);
        float cx = dx * wa + cxa, cy = dy * ha + cya;
        float w = expf(dw) * wa, h = expf(dh) * ha;
        float x1 = cx - 0.5f * w, y1 = cy - 0.5f * h;
        float x2 = cx + 0.5f * w, y2 = cy + 0.5f * h;
        float x1c = fminf(fmaxf(x1, 0.0f), W_IMGF);
        float y1c = fminf(fmaxf(y1, 0.0f), H_IMGF);
        float x2c = fminf(fmaxf(x2, 0.0f), W_IMGF);
        float y2c = fminf(fmaxf(y2, 0.0f), H_IMGF);
        int valid = ((x2c - x1c) >= MIN_SZ) && ((y2c - y1c) >= MIN_SZ);
        mx = fmaxf(fmaxf(x1c, y1c), fmaxf(x2c, y2c));
        size_t rp = (size_t)b * NSEL + r;
        boxes_r[rp * 4 + 0] = x1c; boxes_r[rp * 4 + 1] = y1c;
        boxes_r[rp * 4 + 2] = x2c; boxes_r[rp * 4 + 3] = y2c;
        score_r[rp] = score;
        size_t pp = (size_t)b * NSEL + p;
        boxes_l[pp * 4 + 0] = x1c; boxes_l[pp * 4 + 1] = y1c;
        boxes_l[pp * 4 + 2] = x2c; boxes_l[pp * 4 + 3] = y2c;
        valid_l[pp] = valid;
        rankmap[pp] = r;
    }
    #pragma unroll
    for (int o = 32; o > 0; o >>= 1)
        mx = fmaxf(mx, __shfl_xor(mx, o));
    if ((tid & 63) == 0) wmax[tid >> 6] = mx;
    __syncthreads();
    if (tid == 0) {
        float m2 = wmax[0];
        #pragma unroll
        for (int i = 1; i < 16; ++i) m2 = fmaxf(m2, wmax[i]);
        boxmax5[b * 5 + blockIdx.x] = __float_as_uint(m2);
    }
}

// ---------- K5: mask (full grid, R7 body) + resolve/output done-counter epilogues ----------
// grid (16,4,NBL) x 256. Every block bumps done1[bl]; the 64th (last) runs the
// R7-verified k_resolve body inline (wave 0 computes; DMA double-buffered LDS).
// After resolve, bump done2[b]; the last of 5 levels runs the k_output body
// (256-thread variant). Heavy IoU compute keeps its full-machine grid (R8's
// mistake was moving it onto 20 CUs).
__global__ __launch_bounds__(256) void k_maskro(const float* __restrict__ boxes_l,
                                                const unsigned* __restrict__ boxmax5,
                                                unsigned long long* __restrict__ mask,
                                                const int* __restrict__ valid_l,
                                                const int* __restrict__ rankmap,
                                                int* __restrict__ keep_r,
                                                unsigned* __restrict__ done1,
                                                unsigned* __restrict__ done2,
                                                const float* __restrict__ boxes_r,
                                                const float* __restrict__ score_r,
                                                float* __restrict__ out) {
    __shared__ float cb[64][5];                                   // 1,280 B
    __shared__ __align__(16) unsigned long long sbufA[64 * 16];   // 8 KB
    __shared__ __align__(16) unsigned long long sbufB[64 * 16];   // 8 KB
    __shared__ int ps[256];
    __shared__ int s_flag;
    const int bl = blockIdx.z;
    const int b = bl / NLVL, l = bl - b * NLVL;
    const int kl = lvl_k(l);
    const int w = blockIdx.x, rg = blockIdx.y;
    const int tid = threadIdx.x;     // 256
    const bool act = (rg * 256 < kl);

    // ---- mask body (R7 k_mask, returns replaced by guards) ----
    if (act) {
        float M = __uint_as_float(boxmax5[b * 5 + 0]);
        #pragma unroll
        for (int j = 1; j < 5; ++j) M = fmaxf(M, __uint_as_float(boxmax5[b * 5 + j]));
        M += 1.0f;
        float off = (float)l * M;
        int j0 = w * 64;
        if (tid < 64) {
            int j = j0 + tid;
            if (j < kl) {
                const float* bp = boxes_l + ((size_t)b * NSEL + l * 1000 + j) * 4;
                float x1 = bp[0] + off, y1 = bp[1] + off, x2 = bp[2] + off, y2 = bp[3] + off;
                cb[tid][0] = x1; cb[tid][1] = y1; cb[tid][2] = x2; cb[tid][3] = y2;
                cb[tid][4] = (x2 - x1) * (y2 - y1);
            }
        }
        __syncthreads();
        int i = rg * 256 + tid;
        if (i < kl) {
            unsigned long long word = 0;
            if (j0 + 63 > i) {
                const float* bp = boxes_l + ((size_t)b * NSEL + l * 1000 + i) * 4;
                float ix1 = bp[0] + off, iy1 = bp[1] + off, ix2 = bp[2] + off, iy2 = bp[3] + off;
                float ai = (ix2 - ix1) * (iy2 - iy1);
                int jmax = min(64, kl - j0);
                for (int bb = 0; bb < jmax; ++bb) {
                    int jj = j0 + bb;
                    if (jj <= i) continue;
                    float ltx = fmaxf(ix1, cb[bb][0]), lty = fmaxf(iy1, cb[bb][1]);
                    float rbx = fminf(ix2, cb[bb][2]), rby = fminf(iy2, cb[bb][3]);
                    float ww = fmaxf(rbx - ltx, 0.0f), hh = fmaxf(rby - lty, 0.0f);
                    float inter = ww * hh;
                    float iou = inter / ((ai + cb[bb][4]) - inter);  // NaN>th == false
                    if (iou > NMS_TH) word |= (1ULL << bb);
                }
            }
            mask[((size_t)bl * 1024 + i) * 16 + w] = word;
        }
    }

    // ---- count completion of this bl's 64 mask blocks ----
    __syncthreads();
    if (tid == 0) {
        __threadfence();   // agent release: mask stores visible
        unsigned old = __hip_atomic_fetch_add(done1 + bl, 1u,
                                              __ATOMIC_ACQ_REL, __HIP_MEMORY_SCOPE_AGENT);
        s_flag = (old == 63);
        if (old == 63) __threadfence();   // agent acquire
    }
    __syncthreads();
    if (!s_flag) return;

    // ---- resolve epilogue (R7 k_resolve body; wave 0 computes, all sync) ----
    const int lane = tid & 63;
    const int base = b * NSEL + l * 1000;
    const int nch = (kl + 63) >> 6;   // 16 or 12
    const char* mbyte = (const char*)(mask + (size_t)bl * 1024 * 16);
    unsigned long long keep_w = 0;
    if (tid < 64) {
        for (int c = 0; c < 16; ++c) {
            int q = c * 64 + lane;
            int vv = (q < kl) ? valid_l[base + q] : 0;
            unsigned long long bm = __ballot(vv);
            if (lane == c) keep_w = bm;
        }
        const char* g0 = mbyte + (size_t)lane * 16;
        #pragma unroll
        for (int j = 0; j < 8; ++j)
            async_cp16(g0 + j * 1024, (char*)sbufA + j * 1024);
    }
    for (int c = 0; c < nch; ++c) {
        __syncthreads();                       // drains vmcnt: chunk c staged
        if (tid < 64) {
            unsigned long long* cur = (c & 1) ? sbufB : sbufA;
            unsigned long long* nxt = (c & 1) ? sbufA : sbufB;
            if (c + 1 < nch) {
                const char* g1 = mbyte + (size_t)(c + 1) * 8192 + (size_t)lane * 16;
                #pragma unroll
                for (int j = 0; j < 8; ++j)
                    async_cp16(g1 + j * 1024, (char*)nxt + j * 1024);
            }
            unsigned long long kw = __shfl(keep_w, c);   // uniform in wave
            if (kw) {
                // diagonal word (word c of this lane's row)
                unsigned long long diag = cur[lane * 16 + c];
                unsigned dlo = (unsigned)diag, dhi = (unsigned)(diag >> 32);
                unsigned long long nz = __ballot(diag != 0ULL);
                unsigned long long rem = kw & nz;
                while (rem) {
                    int rr = __ffsll((long long)rem) - 1;
                    unsigned lo = __builtin_amdgcn_readlane(dlo, rr);
                    unsigned hi = __builtin_amdgcn_readlane(dhi, rr);
                    unsigned long long d = ((unsigned long long)hi << 32) | lo;
                    kw &= ~d;
                    rem &= ~(d | (1ULL << rr));
                }
                // batched cross-chunk suppression: lane w<16 ORs word w of kept rows
                unsigned long long supp = 0;
                if (lane < 16) {
                    #pragma unroll
                    for (int rr = 0; rr < 64; ++rr) {
                        unsigned long long mm = cur[rr * 16 + lane];
                        supp |= (((kw >> rr) & 1ULL) ? mm : 0ULL);
                    }
                }
                if (lane == c) keep_w = kw;
                else if (lane < 16 && lane > c) keep_w &= ~supp;
            }
        }
    }
    __syncthreads();
    if (tid < 64) {
        // scatter keep bits to global-rank order
        for (int c = 0; c < 16; ++c) {
            unsigned long long kwc = __shfl(keep_w, c);
            int q = c * 64 + lane;
            if (q < kl)
                keep_r[b * NSEL + rankmap[base + q]] = (int)((kwc >> lane) & 1ULL);
        }
    }
    __syncthreads();   // drain keep_r stores before release

    // ---- output epilogue (last level of image b) ----
    if (tid == 0) {
        __threadfence();   // agent release: keep_r visible
        unsigned old = __hip_atomic_fetch_add(done2 + b, 1u,
                                              __ATOMIC_ACQ_REL, __HIP_MEMORY_SCOPE_AGENT);
        s_flag = (old == NLVL - 1);
        if (old == NLVL - 1) __threadfence();   // agent acquire
    }
    __syncthreads();
    if (!s_flag) return;

    // R7 k_output body, 256-thread variant (CH=19: 19*256 = 4864 >= 4741)
    float* ob = out + (size_t)b * POST_NMS * 4;
    float* osc = out + (size_t)B_IMGS * POST_NMS * 4 + (size_t)b * POST_NMS;
    for (int p = tid; p < POST_NMS; p += 256) {
        ob[p * 4 + 0] = 0.0f; ob[p * 4 + 1] = 0.0f;
        ob[p * 4 + 2] = 0.0f; ob[p * 4 + 3] = 0.0f;
        osc[p] = NEGV;
    }
    __syncthreads();
    const int CH = 19;
    int basei = tid * CH;
    int c0 = 0;
    #pragma unroll
    for (int k = 0; k < CH; ++k) {
        int rr = basei + k;
        if (rr < NSEL) c0 += keep_r[b * NSEL + rr];
    }
    ps[tid] = c0;
    __syncthreads();
    for (int ofs = 1; ofs < 256; ofs <<= 1) {
        int v = (tid >= ofs) ? ps[tid - ofs] : 0;
        __syncthreads();
        ps[tid] += v;
        __syncthreads();
    }
    int p = ps[tid] - c0;   // exclusive prefix
    #pragma unroll
    for (int k = 0; k < CH; ++k) {
        int rr = basei + k;
        if (rr < NSEL && keep_r[b * NSEL + rr]) {
            if (p < POST_NMS) {
                const float* bp = boxes_r + ((size_t)b * NSEL + rr) * 4;
                ob[p * 4 + 0] = bp[0]; ob[p * 4 + 1] = bp[1];
                ob[p * 4 + 2] = bp[2]; ob[p * 4 + 3] = bp[3];
                osc[p] = score_r[(size_t)b * NSEL + rr];
            }
            ++p;
        }
    }
}

extern "C" void kernel_launch(void* const* d_in, const int* in_sizes, int n_in,
                              void* d_out, int out_size, void* d_ws, size_t ws_size,
                              hipStream_t stream) {
    const float* obj     = (const float*)d_in[0];   // [4, 242991]
    const float* deltas  = (const float*)d_in[1];   // [4, 242991, 4]
    const float* anchors = (const float*)d_in[2];   // [242991, 4]
    float* out = (float*)d_out;                     // [4,1000,4] ++ [4,1000]

    char* ws = (char*)d_ws;
    unsigned*            boxmax5 = (unsigned*)(ws + OFF_BM5);
    unsigned*            cnt     = (unsigned*)(ws + OFF_CNT);
    unsigned*            done1   = (unsigned*)(ws + OFF_DONE1);
    unsigned*            done2   = (unsigned*)(ws + OFF_DONE2);
    unsigned*            hist_sl = (unsigned*)(ws + OFF_HSL);
    unsigned*            part_sl = (unsigned*)(ws + OFF_PSL);
    unsigned long long*  cand    = (unsigned long long*)(ws + OFF_CAND);
    unsigned long long*  sel     = (unsigned long long*)(ws + OFF_SEL);
    float*               boxes_r = (float*)(ws + OFF_BOXR);
    float*               score_r = (float*)(ws + OFF_SCR);
    float*               boxes_l = (float*)(ws + OFF_BOXL);
    int*                 valid_l = (int*)(ws + OFF_VAL);
    int*                 rankmap = (int*)(ws + OFF_RMAP);
    int*                 keep_r  = (int*)(ws + OFF_KEEP);
    unsigned long long*  maskp   = (unsigned long long*)(ws + OFF_MASK);

    (void)in_sizes; (void)n_in; (void)out_size; (void)ws_size; (void)WS_NEED;

    // No memset: hist/part slices are plain-store overwritten; cnt+done1+done2
    // zeroed by k_hist's l4 block (kernel-boundary visibility); boxmax5 is
    // plain-stored by k_decode; keep_r fully written before any read.
    k_hist<<<B_IMGS * HBLK_PER_IMG, 512, 0, stream>>>(obj, hist_sl, part_sl, cnt);
    k_compact<<<B_IMGS * CBLK_PER_IMG, 256, 0, stream>>>(obj, hist_sl, part_sl, cnt, cand);
    k_sort<<<NBL, 1024, 0, stream>>>(cand, cnt, sel);
    k_decode<<<dim3(5, B_IMGS), 1024, 0, stream>>>(
        deltas, anchors, sel, boxes_r, score_r, boxes_l, valid_l, rankmap, boxmax5);
    k_maskro<<<dim3(16, 4, NBL), 256, 0, stream>>>(
        boxes_l, boxmax5, maskp, valid_l, rankmap, keep_r, done1, done2,
        boxes_r, score_r, out);
}

// Round 10
// 192.967 us; speedup vs baseline: 1.6457x; 1.2482x over previous
//
#include <hip/hip_runtime.h>
#include <stdint.h>

// Disable FMA contraction file-wide: we must replicate the reference's
// per-op f32 rounding (decode + IoU) to avoid NMS decision flips.
#pragma clang fp contract(off)

#define B_IMGS   4
#define NLVL     5
#define A_TOTAL  242991
#define NSEL     4741          // 1000*4 + 741
#define NBUCK    8192          // 13-bit buckets: sign+exp+4 mantissa (os>>19)
#define BSHIFT   19
#define CAND_CAP 2048
#define POST_NMS 1000
#define NBL      (B_IMGS * NLVL)
#define NMS_TH   0.7f
#define NEGV     (-1e10f)
#define W_IMGF   1216.0f
#define H_IMGF   800.0f
#define MIN_SZ   1e-3f
#define BBOX_CLIP 4.135166556742356f   // log(1000/16), rounded to f32 by compiler

#define NSLICE_PER_IMG 34      // hist slices per image (l0:24 l1:6 l2:2 l3:1 l4:1-unused)

// ---------- level helpers ----------
__device__ __forceinline__ int lvl_k(int l) { return (l == 4) ? 741 : 1000; }

// ---------- order-preserving float<->uint ----------
__device__ __forceinline__ unsigned flipf(float f) {
    unsigned u = __float_as_uint(f);
    return u ^ (unsigned)(((int)u >> 31) | 0x80000000);
}
__device__ __forceinline__ float unflipf(unsigned os) {
    unsigned u = (os & 0x80000000u) ? (os ^ 0x80000000u) : ~os;
    return __uint_as_float(u);
}

// ---------- async global->LDS DMA (16B per lane, wave-uniform LDS base) ----------
__device__ __forceinline__ void async_cp16(const void* g, void* l) {
    __builtin_amdgcn_global_load_lds(
        (const __attribute__((address_space(1))) unsigned*)g,
        (__attribute__((address_space(3))) unsigned*)l,
        16, 0, 0);
}

// ---------- workspace layout (NOTHING pre-zeroed; counters zeroed by k_hist) ----------
static constexpr size_t OFF_BM    = 0;                                        // f32[4]
static constexpr size_t OFF_CNT   = 128;                                      // u32[20]
static constexpr size_t OFF_DI    = 208;                                      // u32[4] sortdec done
static constexpr size_t OFF_D2    = 224;                                      // u32[4] resout done
static constexpr size_t OFF_HSL   = 256;                                      // u32[4*34*8192]
static constexpr size_t OFF_PSL   = OFF_HSL  + (size_t)B_IMGS * NSLICE_PER_IMG * NBUCK * 4;
static constexpr size_t OFF_CAND  = OFF_PSL  + (size_t)B_IMGS * NSLICE_PER_IMG * 256 * 4;
static constexpr size_t OFF_SEL   = OFF_CAND + (size_t)NBL * CAND_CAP * 8;
static constexpr size_t OFF_BOXR  = OFF_SEL  + (size_t)B_IMGS * NSEL * 8;
static constexpr size_t OFF_SCR   = OFF_BOXR + (size_t)B_IMGS * NSEL * 16;
static constexpr size_t OFF_BOXL  = OFF_SCR  + (size_t)B_IMGS * NSEL * 4;
static constexpr size_t OFF_VAL   = OFF_BOXL + (size_t)B_IMGS * NSEL * 16;
static constexpr size_t OFF_RMAP  = OFF_VAL  + (size_t)B_IMGS * NSEL * 4;
static constexpr size_t OFF_KEEP  = OFF_RMAP + (size_t)B_IMGS * NSEL * 4;
static constexpr size_t OFF_MASK  = (OFF_KEEP + (size_t)B_IMGS * NSEL * 4 + 15) & ~(size_t)15;
static constexpr size_t WS_NEED   = OFF_MASK + (size_t)NBL * 1024 * 16 * 8;   // ~8.5 MB

// ---------- K1: per-span LDS histogram -> private global slice (no atomics) ----------
// 34 blocks/image, 512 threads. l4 block zeroes cnt[20]+di[4]+d2[4] instead.
#define HBLK_PER_IMG 34
__global__ __launch_bounds__(512) void k_hist(const float* __restrict__ obj,
                                              unsigned* __restrict__ hist_sl,
                                              unsigned* __restrict__ part_sl,
                                              unsigned* __restrict__ cntz) {
    __shared__ __align__(16) unsigned lh[NBUCK];   // 32 KB
    const int tid = threadIdx.x;     // 512
    const int b = blockIdx.x / HBLK_PER_IMG;
    const int r = blockIdx.x - b * HBLK_PER_IMG;
    if (r == 33) {                   // l4 block: zero cnt[20]+di[4]+d2[4]
        if (b == 0 && tid < 28) cntz[tid] = 0;
        return;
    }
    int sofs, sub, chunk, lstart, n;
    if (r < 24)      { sofs = 0;  sub = r;      chunk = 7600; lstart = 0;      n = 182400; }
    else if (r < 30) { sofs = 24; sub = r - 24; chunk = 7600; lstart = 182400; n = 45600; }
    else if (r < 32) { sofs = 30; sub = r - 30; chunk = 5700; lstart = 228000; n = 11400; }
    else             { sofs = 32; sub = 0;      chunk = 2850; lstart = 239400; n = 2850; }
    #pragma unroll
    for (int i = tid; i < NBUCK; i += 512) lh[i] = 0;
    __syncthreads();
    const int s0 = sub * chunk;
    const int m = min(chunk, n - s0);
    const float* src = obj + (size_t)b * A_TOTAL + lstart + s0;
    // vectorized histogram (float4 + 4-deep unroll; peel to 16B alignment)
    const int peel0 = (int)(((16u - ((unsigned)(uintptr_t)src & 15u)) & 15u) >> 2);
    const int peel  = (peel0 < m) ? peel0 : m;
    const int nv    = (m - peel) >> 2;
    const float4* s4 = (const float4*)(src + peel);
    const int tail0 = peel + (nv << 2);
#define H1(f) atomicAdd(&lh[flipf(f) >> BSHIFT], 1u)
#define H4(v) do { H1((v).x); H1((v).y); H1((v).z); H1((v).w); } while (0)
    if (tid < peel) H1(src[tid]);
    for (int i = tid; i < nv; i += 2048) {
        if (i + 1536 < nv) {
            float4 a0 = s4[i], a1 = s4[i + 512], a2 = s4[i + 1024], a3 = s4[i + 1536];
            H4(a0); H4(a1); H4(a2); H4(a3);
        } else {
            float4 a0 = s4[i]; H4(a0);
            if (i + 512  < nv) { float4 a = s4[i + 512];  H4(a); }
            if (i + 1024 < nv) { float4 a = s4[i + 1024]; H4(a); }
        }
    }
    for (int i = tail0 + tid; i < m; i += 512) H1(src[i]);
#undef H4
#undef H1
    __syncthreads();
    const int slice = b * NSLICE_PER_IMG + sofs + sub;
    unsigned* gh = hist_sl + (size_t)slice * NBUCK;
    #pragma unroll
    for (int i = tid; i < NBUCK / 4; i += 512)
        ((uint4*)gh)[i] = ((const uint4*)lh)[i];
    if (tid < 256) {
        unsigned s = 0;
        #pragma unroll
        for (int i = 0; i < 32; ++i) s += lh[tid * 32 + ((i + tid) & 31)];
        part_sl[(size_t)slice * 256 + tid] = s;
    }
}

// ---------- K2: threshold (from slice sums) + vectorized compact ----------
#define CBLK_PER_IMG 65
__global__ __launch_bounds__(256) void k_compact(const float* __restrict__ obj,
                                                 const unsigned* __restrict__ hist_sl,
                                                 const unsigned* __restrict__ part_sl,
                                                 unsigned* __restrict__ cnt,
                                                 unsigned long long* __restrict__ cand) {
    __shared__ unsigned long long sbuf[CAND_CAP];   // 16 KB staging
    __shared__ unsigned wsum[4];
    __shared__ unsigned fcnt[4];
    __shared__ unsigned s_cum, s_thr, lcnt, gbase;
    const int tid = threadIdx.x;     // 256
    const int b = blockIdx.x / CBLK_PER_IMG;
    const int r = blockIdx.x - b * CBLK_PER_IMG;
    int l, sofs, nsub, sub, chunk, lstart, n;
    if (r < 48)      { l = 0; sofs = 0;  nsub = 24; sub = r;      chunk = 3800; lstart = 0;      n = 182400; }
    else if (r < 60) { l = 1; sofs = 24; nsub = 6;  sub = r - 48; chunk = 3800; lstart = 182400; n = 45600; }
    else if (r < 63) { l = 2; sofs = 30; nsub = 2;  sub = r - 60; chunk = 3800; lstart = 228000; n = 11400; }
    else if (r == 63){ l = 3; sofs = 32; nsub = 1;  sub = 0;      chunk = 2850; lstart = 239400; n = 2850; }
    else             { l = 4; sofs = 33; nsub = 0;  sub = 0;      chunk = 741;  lstart = 242250; n = 741; }
    const int bl = b * NLVL + l;
    const int kl = lvl_k(l);
    if (tid == 0) { lcnt = 0; s_cum = 0; }
    __syncthreads();
    unsigned T = 0;
    if (l < 4) {   // l4: n <= k -> every element passes, T = 0
        const int lane = tid & 63, wv = tid >> 6;
        // stage 1: suffix(t) over 256 chunk-sums (t = 255 - tid)
        const unsigned* pb = part_sl + (size_t)(b * NSLICE_PER_IMG + sofs) * 256 + (255 - tid);
        unsigned x = 0;
        #pragma unroll 6
        for (int s = 0; s < nsub; ++s) x += pb[(size_t)s * 256];
        #pragma unroll
        for (int d = 1; d < 64; d <<= 1) {
            unsigned up = __shfl_up(x, d);
            if (lane >= d) x += up;
        }
        if (lane == 63) wsum[wv] = x;
        __syncthreads();
        unsigned add = 0;
        #pragma unroll
        for (int u = 0; u < 3; ++u) if (u < wv) add += wsum[u];
        const unsigned suffix = x + add;                 // suffix(255 - tid)
        unsigned long long bm = __ballot(suffix >= (unsigned)kl);
        if (lane == 0) fcnt[wv] = (unsigned)__popcll(bm);
        __syncthreads();
        const int chnk = (int)(fcnt[0] + fcnt[1] + fcnt[2] + fcnt[3]) - 1;
        if ((255 - tid) == chnk + 1) s_cum = suffix;     // 0 if chnk==255
        __syncthreads();
        // stage 2 (wave 0): largest bucket in chunk with suffix >= kl
        if (tid < 64) {
            unsigned y = 0;
            if (tid < 32) {
                const unsigned* hb = hist_sl + (size_t)(b * NSLICE_PER_IMG + sofs) * NBUCK
                                   + chnk * 32 + (31 - tid);
                #pragma unroll 6
                for (int s = 0; s < nsub; ++s) y += hb[(size_t)s * NBUCK];
            }
            #pragma unroll
            for (int d = 1; d < 32; d <<= 1) {
                unsigned up = __shfl_up(y, d);
                if (tid >= d) y += up;
            }
            unsigned suf2 = s_cum + y;                   // bucket i = 31 - tid
            unsigned long long bm2 = __ballot((tid < 32) && (suf2 >= (unsigned)kl));
            if (tid == 0) {
                int istar = (int)__popcll(bm2) - 1;
                s_thr = (unsigned)(chnk * 32 + istar);
            }
        }
        __syncthreads();
        T = s_thr;
    }
    // ---- vectorized pass filter into LDS staging ----
    const int s0 = sub * chunk;
    const int m = min(chunk, n - s0);
    const int abase = lstart + s0;
    const float* src = obj + (size_t)b * A_TOTAL + abase;
    const int peel0 = (int)(((16u - ((unsigned)(uintptr_t)src & 15u)) & 15u) >> 2);
    const int peel  = (peel0 < m) ? peel0 : m;
    const int nv    = (m - peel) >> 2;
    const float4* s4 = (const float4*)(src + peel);
    const int tail0 = peel + (nv << 2);
#define E1(f, idx) do { unsigned os_ = flipf(f); \
    if ((os_ >> BSHIFT) >= T) { \
        unsigned slot = atomicAdd(&lcnt, 1u); \
        if (slot < CAND_CAP) \
            sbuf[slot] = (((unsigned long long)(~os_)) << 32) | (unsigned)(idx); \
    } } while (0)
#define E4(v, gb) do { E1((v).x, (gb)); E1((v).y, (gb) + 1); \
                       E1((v).z, (gb) + 2); E1((v).w, (gb) + 3); } while (0)
    if (tid < peel) E1(src[tid], abase + tid);
    for (int i = tid; i < nv; i += 512) {
        const int gb0 = abase + peel + (i << 2);
        if (i + 256 < nv) {
            float4 a0 = s4[i], a1 = s4[i + 256];
            E4(a0, gb0);
            E4(a1, gb0 + 1024);
        } else {
            float4 a0 = s4[i];
            E4(a0, gb0);
        }
    }
    for (int i = tail0 + tid; i < m; i += 256) E1(src[i], abase + i);
#undef E4
#undef E1
    __syncthreads();
    unsigned total = lcnt; if (total > CAND_CAP) total = CAND_CAP;
    if (tid == 0) gbase = atomicAdd(&cnt[bl], total);
    __syncthreads();
    const unsigned gb = gbase;
    for (unsigned i = tid; i < total; i += 256) {
        unsigned g = gb + i;
        if (g < CAND_CAP)
            cand[(size_t)bl * CAND_CAP + g] = sbuf[i];
    }
}

// ---------- binary search in LDS: #elements < key ----------
__device__ __forceinline__ int lbound_lds(const unsigned long long* s, int len,
                                          unsigned long long key) {
    int lo = 0, hi = len;
    while (lo < hi) {
        int mid = (lo + hi) >> 1;
        if (s[mid] < key) lo = mid + 1; else hi = mid;
    }
    return lo;
}

// ---------- K3: per-(b,level) bitonic sort + last-of-image decode ----------
// 20 blocks x 1024. Sort body verbatim (R7); after writing sel, ACQ_REL done
// counter per image (20 releases total — fences are cheap at this count,
// R9's 1280-fence storm is avoided). Last of 5 blocks per image runs the R7
// decode body looped over the 5 sub-ranges, storing a single boxmax[b].
__global__ __launch_bounds__(1024) void k_sortdec(
        const unsigned long long* __restrict__ cand, const unsigned* __restrict__ cnt,
        unsigned long long* __restrict__ sel,
        const float* __restrict__ deltas, const float* __restrict__ anchors,
        float* __restrict__ boxes_r, float* __restrict__ score_r,
        float* __restrict__ boxes_l, int* __restrict__ valid_l,
        int* __restrict__ rankmap, float* __restrict__ boxmax,
        unsigned* __restrict__ done_i) {
    __shared__ __align__(16) char smem[38016];   // sort keys 16K | decode skey 37,928
    __shared__ float wmax[16];
    __shared__ int s_last;
    const int bl = blockIdx.x;
    const int b = bl / NLVL, l = bl - (bl / NLVL) * NLVL;
    const int tid = threadIdx.x;     // 1024

    // ---- sort phase (R7 k_sort body) ----
    {
        unsigned long long* keys = (unsigned long long*)smem;
        int m = (int)cnt[bl];
        if (m > CAND_CAP) m = CAND_CAP;
        for (int i = tid; i < CAND_CAP; i += 1024)
            keys[i] = (i < m) ? cand[(size_t)bl * CAND_CAP + i] : ~0ULL;
        __syncthreads();
        for (int k = 2; k <= CAND_CAP; k <<= 1) {
            for (int j = k >> 1; j > 0; j >>= 1) {
                int i = ((tid / j) * (j << 1)) + (tid % j);
                int p = i + j;
                bool up = ((i & k) == 0);
                unsigned long long a = keys[i], c = keys[p];
                if ((a > c) == up) { keys[i] = c; keys[p] = a; }
                __syncthreads();
            }
        }
        int kl = lvl_k(l);
        for (int q = tid; q < kl; q += 1024)
            sel[(size_t)b * NSEL + l * 1000 + q] = keys[q];
    }
    __syncthreads();   // drain sel stores (vmcnt) before release
    if (tid == 0) {
        __threadfence();   // agent release: sel visible across XCDs
        unsigned old = __hip_atomic_fetch_add(done_i + b, 1u,
                                              __ATOMIC_ACQ_REL, __HIP_MEMORY_SCOPE_AGENT);
        s_last = (old == NLVL - 1);
        if (old == NLVL - 1) __threadfence();   // agent acquire
    }
    __syncthreads();
    if (!s_last) return;

    // ---- decode phase (R7 k_decode body, looped over 5 sub-ranges) ----
    unsigned long long* skey = (unsigned long long*)smem;
    for (int i = tid; i < NSEL; i += 1024)
        skey[i] = sel[(size_t)b * NSEL + i];
    __syncthreads();
    float mxall = 0.0f;
    for (int sub = 0; sub < 5; ++sub) {
        int p = sub * 1024 + tid;
        bool on = p < NSEL;
        float mx = 0.0f;
        if (on) {
            int l2i = p / 1000;         // p in [4000,4741) -> 4
            int q = p - l2i * 1000;
            unsigned long long key = skey[p];
            unsigned a = (unsigned)(key & 0xFFFFFFFFu);
            unsigned os = ~((unsigned)(key >> 32));
            if (a >= A_TOTAL) a = 0;    // impossible-path safety (MAX padding)
            float score = unflipf(os);
            int r = q;
            for (int l2 = 0; l2 < NLVL; ++l2) {
                if (l2 == l2i) continue;
                r += lbound_lds(skey + l2 * 1000, lvl_k(l2), key);
            }
            const float* dv = deltas + ((size_t)b * A_TOTAL + a) * 4;
            const float* av = anchors + (size_t)a * 4;
            float ax1 = av[0], ay1 = av[1], ax2 = av[2], ay2 = av[3];
            float wa = ax2 - ax1, ha = ay2 - ay1;
            float cxa = ax1 + 0.5f * wa, cya = ay1 + 0.5f * ha;
            float dx = dv[0], dy = dv[1];
            float dw = fminf(dv[2], BBOX_CLIP), dh = fminf(dv[3], BBOX_CLIP);
            float cx = dx * wa + cxa, cy = dy * ha + cya;
            float w = expf(dw) * wa, h = expf(dh) * ha;
            float x1 = cx - 0.5f * w, y1 = cy - 0.5f * h;
            float x2 = cx + 0.5f * w, y2 = cy + 0.5f * h;
            float x1c = fminf(fmaxf(x1, 0.0f), W_IMGF);
            float y1c = fminf(fmaxf(y1, 0.0f), H_IMGF);
            float x2c = fminf(fmaxf(x2, 0.0f), W_IMGF);
            float y2c = fminf(fmaxf(y2, 0.0f), H_IMGF);
            int valid = ((x2c - x1c) >= MIN_SZ) && ((y2c - y1c) >= MIN_SZ);
            mx = fmaxf(fmaxf(x1c, y1c), fmaxf(x2c, y2c));
            size_t rp = (size_t)b * NSEL + r;
            boxes_r[rp * 4 + 0] = x1c; boxes_r[rp * 4 + 1] = y1c;
            boxes_r[rp * 4 + 2] = x2c; boxes_r[rp * 4 + 3] = y2c;
            score_r[rp] = score;
            size_t pp = (size_t)b * NSEL + p;
            boxes_l[pp * 4 + 0] = x1c; boxes_l[pp * 4 + 1] = y1c;
            boxes_l[pp * 4 + 2] = x2c; boxes_l[pp * 4 + 3] = y2c;
            valid_l[pp] = valid;
            rankmap[pp] = r;
        }
        mxall = fmaxf(mxall, mx);
    }
    #pragma unroll
    for (int o = 32; o > 0; o >>= 1)
        mxall = fmaxf(mxall, __shfl_xor(mxall, o));
    if ((tid & 63) == 0) wmax[tid >> 6] = mxall;
    __syncthreads();
    if (tid == 0) {
        float m2 = wmax[0];
        #pragma unroll
        for (int i = 1; i < 16; ++i) m2 = fmaxf(m2, wmax[i]);
        boxmax[b] = m2;    // plain store; k_mask reads after kernel boundary
    }
}

// ---------- K4: suppression bitmask (full grid, R7 body; boxmax single slot) ----------
__global__ void k_mask(const float* __restrict__ boxes_l, const float* __restrict__ boxmax,
                       unsigned long long* __restrict__ mask) {
    int bl = blockIdx.z;
    int b = bl / NLVL, l = bl - b * NLVL;
    int kl = lvl_k(l);
    int w = blockIdx.x, rg = blockIdx.y, tid = threadIdx.x;
    if (rg * 256 >= kl) return;
    float M = boxmax[b] + 1.0f;
    float off = (float)l * M;
    __shared__ float cb[64][5];
    int j0 = w * 64;
    if (tid < 64) {
        int j = j0 + tid;
        if (j < kl) {
            const float* bp = boxes_l + ((size_t)b * NSEL + l * 1000 + j) * 4;
            float x1 = bp[0] + off, y1 = bp[1] + off, x2 = bp[2] + off, y2 = bp[3] + off;
            cb[tid][0] = x1; cb[tid][1] = y1; cb[tid][2] = x2; cb[tid][3] = y2;
            cb[tid][4] = (x2 - x1) * (y2 - y1);
        }
    }
    __syncthreads();
    int i = rg * 256 + tid;
    if (i >= kl) return;
    unsigned long long word = 0;
    if (j0 + 63 > i) {
        const float* bp = boxes_l + ((size_t)b * NSEL + l * 1000 + i) * 4;
        float ix1 = bp[0] + off, iy1 = bp[1] + off, ix2 = bp[2] + off, iy2 = bp[3] + off;
        float ai = (ix2 - ix1) * (iy2 - iy1);
        int jmax = min(64, kl - j0);
        for (int bb = 0; bb < jmax; ++bb) {
            int jj = j0 + bb;
            if (jj <= i) continue;
            float ltx = fmaxf(ix1, cb[bb][0]), lty = fmaxf(iy1, cb[bb][1]);
            float rbx = fminf(ix2, cb[bb][2]), rby = fminf(iy2, cb[bb][3]);
            float ww = fmaxf(rbx - ltx, 0.0f), hh = fmaxf(rby - lty, 0.0f);
            float inter = ww * hh;
            float iou = inter / ((ai + cb[bb][4]) - inter);   // NaN>th == false, matches jnp
            if (iou > NMS_TH) word |= (1ULL << bb);
        }
    }
    mask[((size_t)bl * 1024 + i) * 16 + w] = word;
}

// ---------- K5: resolve (R9-verified 256-thread body) + last-of-image output ----------
// 20 blocks x 256. Wave 0 runs the greedy resolve with DMA double-buffered
// LDS; then ACQ_REL done2 counter (20 releases); last of 5 blocks per image
// runs the R9-verified 256-thread output body.
__global__ __launch_bounds__(256) void k_resout(const int* __restrict__ valid_l,
                                                const int* __restrict__ rankmap,
                                                const unsigned long long* __restrict__ mask,
                                                int* __restrict__ keep_r,
                                                unsigned* __restrict__ done2,
                                                const float* __restrict__ boxes_r,
                                                const float* __restrict__ score_r,
                                                float* __restrict__ out) {
    __shared__ __align__(16) unsigned long long sbufA[64 * 16];  // 8 KB
    __shared__ __align__(16) unsigned long long sbufB[64 * 16];  // 8 KB
    __shared__ int ps[256];
    __shared__ int s_flag;
    const int bl = blockIdx.x;
    const int b = bl / NLVL, l = bl - b * NLVL;
    const int kl = lvl_k(l);
    const int tid = threadIdx.x;     // 256
    const int lane = tid & 63;
    const int base = b * NSEL + l * 1000;
    const int nch = (kl + 63) >> 6;   // 16 or 12
    const char* mbyte = (const char*)(mask + (size_t)bl * 1024 * 16);

    unsigned long long keep_w = 0;
    if (tid < 64) {
        for (int c = 0; c < 16; ++c) {
            int q = c * 64 + lane;
            int vv = (q < kl) ? valid_l[base + q] : 0;
            unsigned long long bm = __ballot(vv);
            if (lane == c) keep_w = bm;
        }
        const char* g0 = mbyte + (size_t)lane * 16;
        #pragma unroll
        for (int j = 0; j < 8; ++j)
            async_cp16(g0 + j * 1024, (char*)sbufA + j * 1024);
    }
    for (int c = 0; c < nch; ++c) {
        __syncthreads();                       // drains vmcnt: chunk c staged
        if (tid < 64) {
            unsigned long long* cur = (c & 1) ? sbufB : sbufA;
            unsigned long long* nxt = (c & 1) ? sbufA : sbufB;
            if (c + 1 < nch) {
                const char* g1 = mbyte + (size_t)(c + 1) * 8192 + (size_t)lane * 16;
                #pragma unroll
                for (int j = 0; j < 8; ++j)
                    async_cp16(g1 + j * 1024, (char*)nxt + j * 1024);
            }
            unsigned long long kw = __shfl(keep_w, c);   // uniform in wave
            if (kw) {
                // diagonal word (word c of this lane's row)
                unsigned long long diag = cur[lane * 16 + c];
                unsigned dlo = (unsigned)diag, dhi = (unsigned)(diag >> 32);
                unsigned long long nz = __ballot(diag != 0ULL);
                unsigned long long rem = kw & nz;
                while (rem) {
                    int rr = __ffsll((long long)rem) - 1;
                    unsigned lo = __builtin_amdgcn_readlane(dlo, rr);
                    unsigned hi = __builtin_amdgcn_readlane(dhi, rr);
                    unsigned long long d = ((unsigned long long)hi << 32) | lo;
                    kw &= ~d;
                    rem &= ~(d | (1ULL << rr));
                }
                // batched cross-chunk suppression: lane w<16 ORs word w of kept rows
                unsigned long long supp = 0;
                if (lane < 16) {
                    #pragma unroll
                    for (int rr = 0; rr < 64; ++rr) {
                        unsigned long long mm = cur[rr * 16 + lane];
                        supp |= (((kw >> rr) & 1ULL) ? mm : 0ULL);
                    }
                }
                if (lane == c) keep_w = kw;
                else if (lane < 16 && lane > c) keep_w &= ~supp;
            }
        }
    }
    __syncthreads();
    if (tid < 64) {
        // scatter keep bits to global-rank order
        for (int c = 0; c < 16; ++c) {
            unsigned long long kwc = __shfl(keep_w, c);
            int q = c * 64 + lane;
            if (q < kl)
                keep_r[b * NSEL + rankmap[base + q]] = (int)((kwc >> lane) & 1ULL);
        }
    }
    __syncthreads();   // drain keep_r stores before release

    // ---- last-of-image output epilogue (20 releases total) ----
    if (tid == 0) {
        __threadfence();   // agent release: keep_r visible
        unsigned old = __hip_atomic_fetch_add(done2 + b, 1u,
                                              __ATOMIC_ACQ_REL, __HIP_MEMORY_SCOPE_AGENT);
        s_flag = (old == NLVL - 1);
        if (old == NLVL - 1) __threadfence();   // agent acquire
    }
    __syncthreads();
    if (!s_flag) return;

    // R9-verified 256-thread output body (CH=19: 19*256 = 4864 >= 4741)
    float* ob = out + (size_t)b * POST_NMS * 4;
    float* osc = out + (size_t)B_IMGS * POST_NMS * 4 + (size_t)b * POST_NMS;
    for (int p = tid; p < POST_NMS; p += 256) {
        ob[p * 4 + 0] = 0.0f; ob[p * 4 + 1] = 0.0f;
        ob[p * 4 + 2] = 0.0f; ob[p * 4 + 3] = 0.0f;
        osc[p] = NEGV;
    }
    __syncthreads();
    const int CH = 19;
    int basei = tid * CH;
    int c0 = 0;
    #pragma unroll
    for (int k = 0; k < CH; ++k) {
        int rr = basei + k;
        if (rr < NSEL) c0 += keep_r[b * NSEL + rr];
    }
    ps[tid] = c0;
    __syncthreads();
    for (int ofs = 1; ofs < 256; ofs <<= 1) {
        int v = (tid >= ofs) ? ps[tid - ofs] : 0;
        __syncthreads();
        ps[tid] += v;
        __syncthreads();
    }
    int p = ps[tid] - c0;   // exclusive prefix
    #pragma unroll
    for (int k = 0; k < CH; ++k) {
        int rr = basei + k;
        if (rr < NSEL && keep_r[b * NSEL + rr]) {
            if (p < POST_NMS) {
                const float* bp = boxes_r + ((size_t)b * NSEL + rr) * 4;
                ob[p * 4 + 0] = bp[0]; ob[p * 4 + 1] = bp[1];
                ob[p * 4 + 2] = bp[2]; ob[p * 4 + 3] = bp[3];
                osc[p] = score_r[(size_t)b * NSEL + rr];
            }
            ++p;
        }
    }
}

extern "C" void kernel_launch(void* const* d_in, const int* in_sizes, int n_in,
                              void* d_out, int out_size, void* d_ws, size_t ws_size,
                              hipStream_t stream) {
    const float* obj     = (const float*)d_in[0];   // [4, 242991]
    const float* deltas  = (const float*)d_in[1];   // [4, 242991, 4]
    const float* anchors = (const float*)d_in[2];   // [242991, 4]
    float* out = (float*)d_out;                     // [4,1000,4] ++ [4,1000]

    char* ws = (char*)d_ws;
    float*               boxmax  = (float*)(ws + OFF_BM);
    unsigned*            cnt     = (unsigned*)(ws + OFF_CNT);
    unsigned*            done_i  = (unsigned*)(ws + OFF_DI);
    unsigned*            done2   = (unsigned*)(ws + OFF_D2);
    unsigned*            hist_sl = (unsigned*)(ws + OFF_HSL);
    unsigned*            part_sl = (unsigned*)(ws + OFF_PSL);
    unsigned long long*  cand    = (unsigned long long*)(ws + OFF_CAND);
    unsigned long long*  sel     = (unsigned long long*)(ws + OFF_SEL);
    float*               boxes_r = (float*)(ws + OFF_BOXR);
    float*               score_r = (float*)(ws + OFF_SCR);
    float*               boxes_l = (float*)(ws + OFF_BOXL);
    int*                 valid_l = (int*)(ws + OFF_VAL);
    int*                 rankmap = (int*)(ws + OFF_RMAP);
    int*                 keep_r  = (int*)(ws + OFF_KEEP);
    unsigned long long*  maskp   = (unsigned long long*)(ws + OFF_MASK);

    (void)in_sizes; (void)n_in; (void)out_size; (void)ws_size; (void)WS_NEED;

    // No memset: hist/part slices are plain-store overwritten; cnt+done_i+done2
    // zeroed by k_hist's l4 block (kernel-boundary visibility); boxmax is
    // plain-stored by k_sortdec; keep_r fully written before any read.
    k_hist<<<B_IMGS * HBLK_PER_IMG, 512, 0, stream>>>(obj, hist_sl, part_sl, cnt);
    k_compact<<<B_IMGS * CBLK_PER_IMG, 256, 0, stream>>>(obj, hist_sl, part_sl, cnt, cand);
    k_sortdec<<<NBL, 1024, 0, stream>>>(cand, cnt, sel, deltas, anchors,
                                        boxes_r, score_r, boxes_l, valid_l,
                                        rankmap, boxmax, done_i);
    k_mask<<<dim3(16, 4, NBL), 256, 0, stream>>>(boxes_l, boxmax, maskp);
    k_resout<<<NBL, 256, 0, stream>>>(valid_l, rankmap, maskp, keep_r, done2,
                                      boxes_r, score_r, out);
}

// Round 11
// 180.117 us; speedup vs baseline: 1.7631x; 1.0713x over previous
//
#include <hip/hip_runtime.h>
#include <stdint.h>

// Disable FMA contraction file-wide: we must replicate the reference's
// per-op f32 rounding (decode + IoU) to avoid NMS decision flips.
#pragma clang fp contract(off)

#define B_IMGS   4
#define NLVL     5
#define A_TOTAL  242991
#define NSEL     4741          // 1000*4 + 741
#define NBUCK    8192          // 13-bit buckets: sign+exp+4 mantissa (os>>19)
#define BSHIFT   19
#define CAND_CAP 2048
#define POST_NMS 1000
#define NBL      (B_IMGS * NLVL)
#define NMS_TH   0.7f
#define NEGV     (-1e10f)
#define W_IMGF   1216.0f
#define H_IMGF   800.0f
#define MIN_SZ   1e-3f
#define BBOX_CLIP 4.135166556742356f   // log(1000/16), rounded to f32 by compiler

#define NSLICE_PER_IMG 34      // hist slices per image (l0:24 l1:6 l2:2 l3:1 l4:1-unused)

// ---------- level helpers ----------
__device__ __forceinline__ int lvl_k(int l) { return (l == 4) ? 741 : 1000; }

// ---------- order-preserving float<->uint ----------
__device__ __forceinline__ unsigned flipf(float f) {
    unsigned u = __float_as_uint(f);
    return u ^ (unsigned)(((int)u >> 31) | 0x80000000);
}
__device__ __forceinline__ float unflipf(unsigned os) {
    unsigned u = (os & 0x80000000u) ? (os ^ 0x80000000u) : ~os;
    return __uint_as_float(u);
}

// ---------- async global->LDS DMA (16B per lane, wave-uniform LDS base) ----------
__device__ __forceinline__ void async_cp16(const void* g, void* l) {
    __builtin_amdgcn_global_load_lds(
        (const __attribute__((address_space(1))) unsigned*)g,
        (__attribute__((address_space(3))) unsigned*)l,
        16, 0, 0);
}

// ---------- workspace layout (NOTHING pre-zeroed; counters zeroed by k_hist) ----------
static constexpr size_t OFF_BM5   = 0;                                        // u32[20]
static constexpr size_t OFF_CNT   = 128;                                      // u32[20]
static constexpr size_t OFF_DI    = 208;                                      // u32[4] sortdec barrier
static constexpr size_t OFF_D2    = 224;                                      // u32[4] resout done
static constexpr size_t OFF_HSL   = 256;                                      // u32[4*34*8192]
static constexpr size_t OFF_PSL   = OFF_HSL  + (size_t)B_IMGS * NSLICE_PER_IMG * NBUCK * 4;
static constexpr size_t OFF_CAND  = OFF_PSL  + (size_t)B_IMGS * NSLICE_PER_IMG * 256 * 4;
static constexpr size_t OFF_SEL   = OFF_CAND + (size_t)NBL * CAND_CAP * 8;
static constexpr size_t OFF_BOXR  = OFF_SEL  + (size_t)B_IMGS * NSEL * 8;
static constexpr size_t OFF_SCR   = OFF_BOXR + (size_t)B_IMGS * NSEL * 16;
static constexpr size_t OFF_BOXL  = OFF_SCR  + (size_t)B_IMGS * NSEL * 4;
static constexpr size_t OFF_VAL   = OFF_BOXL + (size_t)B_IMGS * NSEL * 16;
static constexpr size_t OFF_RMAP  = OFF_VAL  + (size_t)B_IMGS * NSEL * 4;
static constexpr size_t OFF_KEEP  = OFF_RMAP + (size_t)B_IMGS * NSEL * 4;
static constexpr size_t OFF_MASK  = (OFF_KEEP + (size_t)B_IMGS * NSEL * 4 + 15) & ~(size_t)15;
static constexpr size_t WS_NEED   = OFF_MASK + (size_t)NBL * 1024 * 16 * 8;   // ~8.5 MB

// ---------- K1: per-span LDS histogram -> private global slice (no atomics) ----------
// 34 blocks/image, 512 threads. l4 block zeroes cnt[20]+di[4]+d2[4] instead.
#define HBLK_PER_IMG 34
__global__ __launch_bounds__(512) void k_hist(const float* __restrict__ obj,
                                              unsigned* __restrict__ hist_sl,
                                              unsigned* __restrict__ part_sl,
                                              unsigned* __restrict__ cntz) {
    __shared__ __align__(16) unsigned lh[NBUCK];   // 32 KB
    const int tid = threadIdx.x;     // 512
    const int b = blockIdx.x / HBLK_PER_IMG;
    const int r = blockIdx.x - b * HBLK_PER_IMG;
    if (r == 33) {                   // l4 block: zero cnt[20]+di[4]+d2[4]
        if (b == 0 && tid < 28) cntz[tid] = 0;
        return;
    }
    int sofs, sub, chunk, lstart, n;
    if (r < 24)      { sofs = 0;  sub = r;      chunk = 7600; lstart = 0;      n = 182400; }
    else if (r < 30) { sofs = 24; sub = r - 24; chunk = 7600; lstart = 182400; n = 45600; }
    else if (r < 32) { sofs = 30; sub = r - 30; chunk = 5700; lstart = 228000; n = 11400; }
    else             { sofs = 32; sub = 0;      chunk = 2850; lstart = 239400; n = 2850; }
    #pragma unroll
    for (int i = tid; i < NBUCK; i += 512) lh[i] = 0;
    __syncthreads();
    const int s0 = sub * chunk;
    const int m = min(chunk, n - s0);
    const float* src = obj + (size_t)b * A_TOTAL + lstart + s0;
    // vectorized histogram (float4 + 4-deep unroll; peel to 16B alignment)
    const int peel0 = (int)(((16u - ((unsigned)(uintptr_t)src & 15u)) & 15u) >> 2);
    const int peel  = (peel0 < m) ? peel0 : m;
    const int nv    = (m - peel) >> 2;
    const float4* s4 = (const float4*)(src + peel);
    const int tail0 = peel + (nv << 2);
#define H1(f) atomicAdd(&lh[flipf(f) >> BSHIFT], 1u)
#define H4(v) do { H1((v).x); H1((v).y); H1((v).z); H1((v).w); } while (0)
    if (tid < peel) H1(src[tid]);
    for (int i = tid; i < nv; i += 2048) {
        if (i + 1536 < nv) {
            float4 a0 = s4[i], a1 = s4[i + 512], a2 = s4[i + 1024], a3 = s4[i + 1536];
            H4(a0); H4(a1); H4(a2); H4(a3);
        } else {
            float4 a0 = s4[i]; H4(a0);
            if (i + 512  < nv) { float4 a = s4[i + 512];  H4(a); }
            if (i + 1024 < nv) { float4 a = s4[i + 1024]; H4(a); }
        }
    }
    for (int i = tail0 + tid; i < m; i += 512) H1(src[i]);
#undef H4
#undef H1
    __syncthreads();
    const int slice = b * NSLICE_PER_IMG + sofs + sub;
    unsigned* gh = hist_sl + (size_t)slice * NBUCK;
    #pragma unroll
    for (int i = tid; i < NBUCK / 4; i += 512)
        ((uint4*)gh)[i] = ((const uint4*)lh)[i];
    if (tid < 256) {
        unsigned s = 0;
        #pragma unroll
        for (int i = 0; i < 32; ++i) s += lh[tid * 32 + ((i + tid) & 31)];
        part_sl[(size_t)slice * 256 + tid] = s;
    }
}

// ---------- K2: threshold (from slice sums) + vectorized compact ----------
#define CBLK_PER_IMG 65
__global__ __launch_bounds__(256) void k_compact(const float* __restrict__ obj,
                                                 const unsigned* __restrict__ hist_sl,
                                                 const unsigned* __restrict__ part_sl,
                                                 unsigned* __restrict__ cnt,
                                                 unsigned long long* __restrict__ cand) {
    __shared__ unsigned long long sbuf[CAND_CAP];   // 16 KB staging
    __shared__ unsigned wsum[4];
    __shared__ unsigned fcnt[4];
    __shared__ unsigned s_cum, s_thr, lcnt, gbase;
    const int tid = threadIdx.x;     // 256
    const int b = blockIdx.x / CBLK_PER_IMG;
    const int r = blockIdx.x - b * CBLK_PER_IMG;
    int l, sofs, nsub, sub, chunk, lstart, n;
    if (r < 48)      { l = 0; sofs = 0;  nsub = 24; sub = r;      chunk = 3800; lstart = 0;      n = 182400; }
    else if (r < 60) { l = 1; sofs = 24; nsub = 6;  sub = r - 48; chunk = 3800; lstart = 182400; n = 45600; }
    else if (r < 63) { l = 2; sofs = 30; nsub = 2;  sub = r - 60; chunk = 3800; lstart = 228000; n = 11400; }
    else if (r == 63){ l = 3; sofs = 32; nsub = 1;  sub = 0;      chunk = 2850; lstart = 239400; n = 2850; }
    else             { l = 4; sofs = 33; nsub = 0;  sub = 0;      chunk = 741;  lstart = 242250; n = 741; }
    const int bl = b * NLVL + l;
    const int kl = lvl_k(l);
    if (tid == 0) { lcnt = 0; s_cum = 0; }
    __syncthreads();
    unsigned T = 0;
    if (l < 4) {   // l4: n <= k -> every element passes, T = 0
        const int lane = tid & 63, wv = tid >> 6;
        // stage 1: suffix(t) over 256 chunk-sums (t = 255 - tid)
        const unsigned* pb = part_sl + (size_t)(b * NSLICE_PER_IMG + sofs) * 256 + (255 - tid);
        unsigned x = 0;
        #pragma unroll 6
        for (int s = 0; s < nsub; ++s) x += pb[(size_t)s * 256];
        #pragma unroll
        for (int d = 1; d < 64; d <<= 1) {
            unsigned up = __shfl_up(x, d);
            if (lane >= d) x += up;
        }
        if (lane == 63) wsum[wv] = x;
        __syncthreads();
        unsigned add = 0;
        #pragma unroll
        for (int u = 0; u < 3; ++u) if (u < wv) add += wsum[u];
        const unsigned suffix = x + add;                 // suffix(255 - tid)
        unsigned long long bm = __ballot(suffix >= (unsigned)kl);
        if (lane == 0) fcnt[wv] = (unsigned)__popcll(bm);
        __syncthreads();
        const int chnk = (int)(fcnt[0] + fcnt[1] + fcnt[2] + fcnt[3]) - 1;
        if ((255 - tid) == chnk + 1) s_cum = suffix;     // 0 if chnk==255
        __syncthreads();
        // stage 2 (wave 0): largest bucket in chunk with suffix >= kl
        if (tid < 64) {
            unsigned y = 0;
            if (tid < 32) {
                const unsigned* hb = hist_sl + (size_t)(b * NSLICE_PER_IMG + sofs) * NBUCK
                                   + chnk * 32 + (31 - tid);
                #pragma unroll 6
                for (int s = 0; s < nsub; ++s) y += hb[(size_t)s * NBUCK];
            }
            #pragma unroll
            for (int d = 1; d < 32; d <<= 1) {
                unsigned up = __shfl_up(y, d);
                if (tid >= d) y += up;
            }
            unsigned suf2 = s_cum + y;                   // bucket i = 31 - tid
            unsigned long long bm2 = __ballot((tid < 32) && (suf2 >= (unsigned)kl));
            if (tid == 0) {
                int istar = (int)__popcll(bm2) - 1;
                s_thr = (unsigned)(chnk * 32 + istar);
            }
        }
        __syncthreads();
        T = s_thr;
    }
    // ---- vectorized pass filter into LDS staging ----
    const int s0 = sub * chunk;
    const int m = min(chunk, n - s0);
    const int abase = lstart + s0;
    const float* src = obj + (size_t)b * A_TOTAL + abase;
    const int peel0 = (int)(((16u - ((unsigned)(uintptr_t)src & 15u)) & 15u) >> 2);
    const int peel  = (peel0 < m) ? peel0 : m;
    const int nv    = (m - peel) >> 2;
    const float4* s4 = (const float4*)(src + peel);
    const int tail0 = peel + (nv << 2);
#define E1(f, idx) do { unsigned os_ = flipf(f); \
    if ((os_ >> BSHIFT) >= T) { \
        unsigned slot = atomicAdd(&lcnt, 1u); \
        if (slot < CAND_CAP) \
            sbuf[slot] = (((unsigned long long)(~os_)) << 32) | (unsigned)(idx); \
    } } while (0)
#define E4(v, gb) do { E1((v).x, (gb)); E1((v).y, (gb) + 1); \
                       E1((v).z, (gb) + 2); E1((v).w, (gb) + 3); } while (0)
    if (tid < peel) E1(src[tid], abase + tid);
    for (int i = tid; i < nv; i += 512) {
        const int gb0 = abase + peel + (i << 2);
        if (i + 256 < nv) {
            float4 a0 = s4[i], a1 = s4[i + 256];
            E4(a0, gb0);
            E4(a1, gb0 + 1024);
        } else {
            float4 a0 = s4[i];
            E4(a0, gb0);
        }
    }
    for (int i = tail0 + tid; i < m; i += 256) E1(src[i], abase + i);
#undef E4
#undef E1
    __syncthreads();
    unsigned total = lcnt; if (total > CAND_CAP) total = CAND_CAP;
    if (tid == 0) gbase = atomicAdd(&cnt[bl], total);
    __syncthreads();
    const unsigned gb = gbase;
    for (unsigned i = tid; i < total; i += 256) {
        unsigned g = gb + i;
        if (g < CAND_CAP)
            cand[(size_t)bl * CAND_CAP + g] = sbuf[i];
    }
}

// ---------- binary search in LDS: #elements < key ----------
__device__ __forceinline__ int lbound_lds(const unsigned long long* s, int len,
                                          unsigned long long key) {
    int lo = 0, hi = len;
    while (lo < hi) {
        int mid = (lo + hi) >> 1;
        if (s[mid] < key) lo = mid + 1; else hi = mid;
    }
    return lo;
}

// ---------- K3: per-(b,level) bitonic sort + per-image barrier + PARALLEL decode ----------
// 20 blocks x 1024. Sort body verbatim (R7). Then a per-image 5-block spin
// barrier (R1/R2-verified fence pattern; only 20 releases total — far from
// R9's 1280-fence storm). After the barrier ALL 5 blocks of the image decode
// their own sub-range (sub = l, exactly R7's blockIdx.x mapping) — decode
// parallelism is R7's 20 blocks, unlike R10's last-arriver 5x serialization.
__global__ __launch_bounds__(1024) void k_sortdec(
        const unsigned long long* __restrict__ cand, const unsigned* __restrict__ cnt,
        unsigned long long* __restrict__ sel,
        const float* __restrict__ deltas, const float* __restrict__ anchors,
        float* __restrict__ boxes_r, float* __restrict__ score_r,
        float* __restrict__ boxes_l, int* __restrict__ valid_l,
        int* __restrict__ rankmap, unsigned* __restrict__ boxmax5,
        unsigned* __restrict__ bar_i) {
    __shared__ __align__(16) char smem[38016];   // sort keys 16K | decode skey 37,928
    __shared__ float wmax[16];
    const int bl = blockIdx.x;
    const int b = bl / NLVL, l = bl - (bl / NLVL) * NLVL;
    const int tid = threadIdx.x;     // 1024

    // ---- sort phase (R7 k_sort body) ----
    {
        unsigned long long* keys = (unsigned long long*)smem;
        int m = (int)cnt[bl];
        if (m > CAND_CAP) m = CAND_CAP;
        for (int i = tid; i < CAND_CAP; i += 1024)
            keys[i] = (i < m) ? cand[(size_t)bl * CAND_CAP + i] : ~0ULL;
        __syncthreads();
        for (int k = 2; k <= CAND_CAP; k <<= 1) {
            for (int j = k >> 1; j > 0; j >>= 1) {
                int i = ((tid / j) * (j << 1)) + (tid % j);
                int p = i + j;
                bool up = ((i & k) == 0);
                unsigned long long a = keys[i], c = keys[p];
                if ((a > c) == up) { keys[i] = c; keys[p] = a; }
                __syncthreads();
            }
        }
        int kl = lvl_k(l);
        for (int q = tid; q < kl; q += 1024)
            sel[(size_t)b * NSEL + l * 1000 + q] = keys[q];
    }
    __syncthreads();   // drain sel stores (vmcnt) before release

    // ---- per-image 5-block spin barrier (all blocks proceed) ----
    if (tid == 0) {
        __threadfence();   // agent release: this block's sel visible
        __hip_atomic_fetch_add(bar_i + b, 1u, __ATOMIC_RELAXED, __HIP_MEMORY_SCOPE_AGENT);
        while (__hip_atomic_load(bar_i + b, __ATOMIC_RELAXED, __HIP_MEMORY_SCOPE_AGENT)
               < (unsigned)NLVL)
            __builtin_amdgcn_s_sleep(2);
        __threadfence();   // agent acquire: all 5 levels' sel visible
    }
    __syncthreads();

    // ---- decode phase (R7 k_decode body; sub = l, full 20-block parallelism) ----
    unsigned long long* skey = (unsigned long long*)smem;
    for (int i = tid; i < NSEL; i += 1024)
        skey[i] = sel[(size_t)b * NSEL + i];
    __syncthreads();
    const int sub = l;
    int p = sub * 1024 + tid;
    bool on = p < NSEL;
    float mx = 0.0f;
    if (on) {
        int l2i = p / 1000;         // p in [4000,4741) -> 4
        int q = p - l2i * 1000;
        unsigned long long key = skey[p];
        unsigned a = (unsigned)(key & 0xFFFFFFFFu);
        unsigned os = ~((unsigned)(key >> 32));
        if (a >= A_TOTAL) a = 0;    // impossible-path safety (MAX padding)
        float score = unflipf(os);
        int r = q;
        for (int l2 = 0; l2 < NLVL; ++l2) {
            if (l2 == l2i) continue;
            r += lbound_lds(skey + l2 * 1000, lvl_k(l2), key);
        }
        const float* dv = deltas + ((size_t)b * A_TOTAL + a) * 4;
        const float* av = anchors + (size_t)a * 4;
        float ax1 = av[0], ay1 = av[1], ax2 = av[2], ay2 = av[3];
        float wa = ax2 - ax1, ha = ay2 - ay1;
        float cxa = ax1 + 0.5f * wa, cya = ay1 + 0.5f * ha;
        float dx = dv[0], dy = dv[1];
        float dw = fminf(dv[2], BBOX_CLIP), dh = fminf(dv[3], BBOX_CLIP);
        float cx = dx * wa + cxa, cy = dy * ha + cya;
        float w = expf(dw) * wa, h = expf(dh) * ha;
        float x1 = cx - 0.5f * w, y1 = cy - 0.5f * h;
        float x2 = cx + 0.5f * w, y2 = cy + 0.5f * h;
        float x1c = fminf(fmaxf(x1, 0.0f), W_IMGF);
        float y1c = fminf(fmaxf(y1, 0.0f), H_IMGF);
        float x2c = fminf(fmaxf(x2, 0.0f), W_IMGF);
        float y2c = fminf(fmaxf(y2, 0.0f), H_IMGF);
        int valid = ((x2c - x1c) >= MIN_SZ) && ((y2c - y1c) >= MIN_SZ);
        mx = fmaxf(fmaxf(x1c, y1c), fmaxf(x2c, y2c));
        size_t rp = (size_t)b * NSEL + r;
        boxes_r[rp * 4 + 0] = x1c; boxes_r[rp * 4 + 1] = y1c;
        boxes_r[rp * 4 + 2] = x2c; boxes_r[rp * 4 + 3] = y2c;
        score_r[rp] = score;
        size_t pp = (size_t)b * NSEL + p;
        boxes_l[pp * 4 + 0] = x1c; boxes_l[pp * 4 + 1] = y1c;
        boxes_l[pp * 4 + 2] = x2c; boxes_l[pp * 4 + 3] = y2c;
        valid_l[pp] = valid;
        rankmap[pp] = r;
    }
    // block max reduction -> private slot (coords >= 0; fmax exact/orderless)
    #pragma unroll
    for (int o = 32; o > 0; o >>= 1)
        mx = fmaxf(mx, __shfl_xor(mx, o));
    if ((tid & 63) == 0) wmax[tid >> 6] = mx;
    __syncthreads();
    if (tid == 0) {
        float m2 = wmax[0];
        #pragma unroll
        for (int i = 1; i < 16; ++i) m2 = fmaxf(m2, wmax[i]);
        boxmax5[b * 5 + sub] = __float_as_uint(m2);
    }
}

// ---------- K4: suppression bitmask (full grid, R7 body; max-of-5 boxmax) ----------
__global__ void k_mask(const float* __restrict__ boxes_l, const unsigned* __restrict__ boxmax5,
                       unsigned long long* __restrict__ mask) {
    int bl = blockIdx.z;
    int b = bl / NLVL, l = bl - b * NLVL;
    int kl = lvl_k(l);
    int w = blockIdx.x, rg = blockIdx.y, tid = threadIdx.x;
    if (rg * 256 >= kl) return;
    float M = __uint_as_float(boxmax5[b * 5 + 0]);
    #pragma unroll
    for (int j = 1; j < 5; ++j) M = fmaxf(M, __uint_as_float(boxmax5[b * 5 + j]));
    M += 1.0f;
    float off = (float)l * M;
    __shared__ float cb[64][5];
    int j0 = w * 64;
    if (tid < 64) {
        int j = j0 + tid;
        if (j < kl) {
            const float* bp = boxes_l + ((size_t)b * NSEL + l * 1000 + j) * 4;
            float x1 = bp[0] + off, y1 = bp[1] + off, x2 = bp[2] + off, y2 = bp[3] + off;
            cb[tid][0] = x1; cb[tid][1] = y1; cb[tid][2] = x2; cb[tid][3] = y2;
            cb[tid][4] = (x2 - x1) * (y2 - y1);
        }
    }
    __syncthreads();
    int i = rg * 256 + tid;
    if (i >= kl) return;
    unsigned long long word = 0;
    if (j0 + 63 > i) {
        const float* bp = boxes_l + ((size_t)b * NSEL + l * 1000 + i) * 4;
        float ix1 = bp[0] + off, iy1 = bp[1] + off, ix2 = bp[2] + off, iy2 = bp[3] + off;
        float ai = (ix2 - ix1) * (iy2 - iy1);
        int jmax = min(64, kl - j0);
        for (int bb = 0; bb < jmax; ++bb) {
            int jj = j0 + bb;
            if (jj <= i) continue;
            float ltx = fmaxf(ix1, cb[bb][0]), lty = fmaxf(iy1, cb[bb][1]);
            float rbx = fminf(ix2, cb[bb][2]), rby = fminf(iy2, cb[bb][3]);
            float ww = fmaxf(rbx - ltx, 0.0f), hh = fmaxf(rby - lty, 0.0f);
            float inter = ww * hh;
            float iou = inter / ((ai + cb[bb][4]) - inter);   // NaN>th == false, matches jnp
            if (iou > NMS_TH) word |= (1ULL << bb);
        }
    }
    mask[((size_t)bl * 1024 + i) * 16 + w] = word;
}

// ---------- K5: resolve (R9/R10-verified 256-thread body) + last-of-image output ----------
// 20 blocks x 256. Wave 0 runs the greedy resolve with DMA double-buffered
// LDS; then ACQ_REL done2 counter (20 releases); last of 5 blocks per image
// runs the verified 256-thread output body.
__global__ __launch_bounds__(256) void k_resout(const int* __restrict__ valid_l,
                                                const int* __restrict__ rankmap,
                                                const unsigned long long* __restrict__ mask,
                                                int* __restrict__ keep_r,
                                                unsigned* __restrict__ done2,
                                                const float* __restrict__ boxes_r,
                                                const float* __restrict__ score_r,
                                                float* __restrict__ out) {
    __shared__ __align__(16) unsigned long long sbufA[64 * 16];  // 8 KB
    __shared__ __align__(16) unsigned long long sbufB[64 * 16];  // 8 KB
    __shared__ int ps[256];
    __shared__ int s_flag;
    const int bl = blockIdx.x;
    const int b = bl / NLVL, l = bl - b * NLVL;
    const int kl = lvl_k(l);
    const int tid = threadIdx.x;     // 256
    const int lane = tid & 63;
    const int base = b * NSEL + l * 1000;
    const int nch = (kl + 63) >> 6;   // 16 or 12
    const char* mbyte = (const char*)(mask + (size_t)bl * 1024 * 16);

    unsigned long long keep_w = 0;
    if (tid < 64) {
        for (int c = 0; c < 16; ++c) {
            int q = c * 64 + lane;
            int vv = (q < kl) ? valid_l[base + q] : 0;
            unsigned long long bm = __ballot(vv);
            if (lane == c) keep_w = bm;
        }
        const char* g0 = mbyte + (size_t)lane * 16;
        #pragma unroll
        for (int j = 0; j < 8; ++j)
            async_cp16(g0 + j * 1024, (char*)sbufA + j * 1024);
    }
    for (int c = 0; c < nch; ++c) {
        __syncthreads();                       // drains vmcnt: chunk c staged
        if (tid < 64) {
            unsigned long long* cur = (c & 1) ? sbufB : sbufA;
            unsigned long long* nxt = (c & 1) ? sbufA : sbufB;
            if (c + 1 < nch) {
                const char* g1 = mbyte + (size_t)(c + 1) * 8192 + (size_t)lane * 16;
                #pragma unroll
                for (int j = 0; j < 8; ++j)
                    async_cp16(g1 + j * 1024, (char*)nxt + j * 1024);
            }
            unsigned long long kw = __shfl(keep_w, c);   // uniform in wave
            if (kw) {
                // diagonal word (word c of this lane's row)
                unsigned long long diag = cur[lane * 16 + c];
                unsigned dlo = (unsigned)diag, dhi = (unsigned)(diag >> 32);
                unsigned long long nz = __ballot(diag != 0ULL);
                unsigned long long rem = kw & nz;
                while (rem) {
                    int rr = __ffsll((long long)rem) - 1;
                    unsigned lo = __builtin_amdgcn_readlane(dlo, rr);
                    unsigned hi = __builtin_amdgcn_readlane(dhi, rr);
                    unsigned long long d = ((unsigned long long)hi << 32) | lo;
                    kw &= ~d;
                    rem &= ~(d | (1ULL << rr));
                }
                // batched cross-chunk suppression: lane w<16 ORs word w of kept rows
                unsigned long long supp = 0;
                if (lane < 16) {
                    #pragma unroll
                    for (int rr = 0; rr < 64; ++rr) {
                        unsigned long long mm = cur[rr * 16 + lane];
                        supp |= (((kw >> rr) & 1ULL) ? mm : 0ULL);
                    }
                }
                if (lane == c) keep_w = kw;
                else if (lane < 16 && lane > c) keep_w &= ~supp;
            }
        }
    }
    __syncthreads();
    if (tid < 64) {
        // scatter keep bits to global-rank order
        for (int c = 0; c < 16; ++c) {
            unsigned long long kwc = __shfl(keep_w, c);
            int q = c * 64 + lane;
            if (q < kl)
                keep_r[b * NSEL + rankmap[base + q]] = (int)((kwc >> lane) & 1ULL);
        }
    }
    __syncthreads();   // drain keep_r stores before release

    // ---- last-of-image output epilogue (20 releases total) ----
    if (tid == 0) {
        __threadfence();   // agent release: keep_r visible
        unsigned old = __hip_atomic_fetch_add(done2 + b, 1u,
                                              __ATOMIC_ACQ_REL, __HIP_MEMORY_SCOPE_AGENT);
        s_flag = (old == NLVL - 1);
        if (old == NLVL - 1) __threadfence();   // agent acquire
    }
    __syncthreads();
    if (!s_flag) return;

    // verified 256-thread output body (CH=19: 19*256 = 4864 >= 4741)
    float* ob = out + (size_t)b * POST_NMS * 4;
    float* osc = out + (size_t)B_IMGS * POST_NMS * 4 + (size_t)b * POST_NMS;
    for (int p = tid; p < POST_NMS; p += 256) {
        ob[p * 4 + 0] = 0.0f; ob[p * 4 + 1] = 0.0f;
        ob[p * 4 + 2] = 0.0f; ob[p * 4 + 3] = 0.0f;
        osc[p] = NEGV;
    }
    __syncthreads();
    const int CH = 19;
    int basei = tid * CH;
    int c0 = 0;
    #pragma unroll
    for (int k = 0; k < CH; ++k) {
        int rr = basei + k;
        if (rr < NSEL) c0 += keep_r[b * NSEL + rr];
    }
    ps[tid] = c0;
    __syncthreads();
    for (int ofs = 1; ofs < 256; ofs <<= 1) {
        int v = (tid >= ofs) ? ps[tid - ofs] : 0;
        __syncthreads();
        ps[tid] += v;
        __syncthreads();
    }
    int p = ps[tid] - c0;   // exclusive prefix
    #pragma unroll
    for (int k = 0; k < CH; ++k) {
        int rr = basei + k;
        if (rr < NSEL && keep_r[b * NSEL + rr]) {
            if (p < POST_NMS) {
                const float* bp = boxes_r + ((size_t)b * NSEL + rr) * 4;
                ob[p * 4 + 0] = bp[0]; ob[p * 4 + 1] = bp[1];
                ob[p * 4 + 2] = bp[2]; ob[p * 4 + 3] = bp[3];
                osc[p] = score_r[(size_t)b * NSEL + rr];
            }
            ++p;
        }
    }
}

extern "C" void kernel_launch(void* const* d_in, const int* in_sizes, int n_in,
                              void* d_out, int out_size, void* d_ws, size_t ws_size,
                              hipStream_t stream) {
    const float* obj     = (const float*)d_in[0];   // [4, 242991]
    const float* deltas  = (const float*)d_in[1];   // [4, 242991, 4]
    const float* anchors = (const float*)d_in[2];   // [242991, 4]
    float* out = (float*)d_out;                     // [4,1000,4] ++ [4,1000]

    char* ws = (char*)d_ws;
    unsigned*            boxmax5 = (unsigned*)(ws + OFF_BM5);
    unsigned*            cnt     = (unsigned*)(ws + OFF_CNT);
    unsigned*            bar_i   = (unsigned*)(ws + OFF_DI);
    unsigned*            done2   = (unsigned*)(ws + OFF_D2);
    unsigned*            hist_sl = (unsigned*)(ws + OFF_HSL);
    unsigned*            part_sl = (unsigned*)(ws + OFF_PSL);
    unsigned long long*  cand    = (unsigned long long*)(ws + OFF_CAND);
    unsigned long long*  sel     = (unsigned long long*)(ws + OFF_SEL);
    float*               boxes_r = (float*)(ws + OFF_BOXR);
    float*               score_r = (float*)(ws + OFF_SCR);
    float*               boxes_l = (float*)(ws + OFF_BOXL);
    int*                 valid_l = (int*)(ws + OFF_VAL);
    int*                 rankmap = (int*)(ws + OFF_RMAP);
    int*                 keep_r  = (int*)(ws + OFF_KEEP);
    unsigned long long*  maskp   = (unsigned long long*)(ws + OFF_MASK);

    (void)in_sizes; (void)n_in; (void)out_size; (void)ws_size; (void)WS_NEED;

    // No memset: hist/part slices are plain-store overwritten; cnt+bar_i+done2
    // zeroed by k_hist's l4 block (kernel-boundary visibility); boxmax5 is
    // plain-stored by k_sortdec; keep_r fully written before any read.
    k_hist<<<B_IMGS * HBLK_PER_IMG, 512, 0, stream>>>(obj, hist_sl, part_sl, cnt);
    k_compact<<<B_IMGS * CBLK_PER_IMG, 256, 0, stream>>>(obj, hist_sl, part_sl, cnt, cand);
    k_sortdec<<<NBL, 1024, 0, stream>>>(cand, cnt, sel, deltas, anchors,
                                        boxes_r, score_r, boxes_l, valid_l,
                                        rankmap, boxmax5, bar_i);
    k_mask<<<dim3(16, 4, NBL), 256, 0, stream>>>(boxes_l, boxmax5, maskp);
    k_resout<<<NBL, 256, 0, stream>>>(valid_l, rankmap, maskp, keep_r, done2,
                                      boxes_r, score_r, out);
}

// Round 12
// 179.358 us; speedup vs baseline: 1.7706x; 1.0042x over previous
//
#include <hip/hip_runtime.h>
#include <stdint.h>

// Disable FMA contraction file-wide: we must replicate the reference's
// per-op f32 rounding (decode + IoU) to avoid NMS decision flips.
#pragma clang fp contract(off)

#define B_IMGS   4
#define NLVL     5
#define A_TOTAL  242991
#define NSEL     4741          // 1000*4 + 741
#define NBUCK    8192          // 13-bit buckets: sign+exp+4 mantissa (os>>19)
#define BSHIFT   19
#define CAND_CAP 2048
#define POST_NMS 1000
#define NBL      (B_IMGS * NLVL)
#define NMS_TH   0.7f
#define NEGV     (-1e10f)
#define W_IMGF   1216.0f
#define H_IMGF   800.0f
#define MIN_SZ   1e-3f
#define BBOX_CLIP 4.135166556742356f   // log(1000/16), rounded to f32 by compiler

#define NSLICE_PER_IMG 34      // hist slices per image (l0:24 l1:6 l2:2 l3:1 l4:1-unused)

// ---------- level helpers ----------
__device__ __forceinline__ int lvl_k(int l) { return (l == 4) ? 741 : 1000; }

// ---------- order-preserving float<->uint ----------
__device__ __forceinline__ unsigned flipf(float f) {
    unsigned u = __float_as_uint(f);
    return u ^ (unsigned)(((int)u >> 31) | 0x80000000);
}
__device__ __forceinline__ float unflipf(unsigned os) {
    unsigned u = (os & 0x80000000u) ? (os ^ 0x80000000u) : ~os;
    return __uint_as_float(u);
}

// ---------- async global->LDS DMA (16B per lane, wave-uniform LDS base) ----------
__device__ __forceinline__ void async_cp16(const void* g, void* l) {
    __builtin_amdgcn_global_load_lds(
        (const __attribute__((address_space(1))) unsigned*)g,
        (__attribute__((address_space(3))) unsigned*)l,
        16, 0, 0);
}

// ---------- workspace layout (NOTHING pre-zeroed; counters zeroed by k_hist) ----------
static constexpr size_t OFF_BM5   = 0;                                        // u32[20]
static constexpr size_t OFF_CNT   = 128;                                      // u32[20]
static constexpr size_t OFF_DI    = 208;                                      // u32[4] sortdec barrier
static constexpr size_t OFF_D2    = 224;                                      // u32[4] resout done
static constexpr size_t OFF_HSL   = 256;                                      // u32[4*34*8192]
static constexpr size_t OFF_PSL   = OFF_HSL  + (size_t)B_IMGS * NSLICE_PER_IMG * NBUCK * 4;
static constexpr size_t OFF_CAND  = OFF_PSL  + (size_t)B_IMGS * NSLICE_PER_IMG * 256 * 4;
static constexpr size_t OFF_SEL   = OFF_CAND + (size_t)NBL * CAND_CAP * 8;
static constexpr size_t OFF_BOXR  = OFF_SEL  + (size_t)B_IMGS * NSEL * 8;
static constexpr size_t OFF_SCR   = OFF_BOXR + (size_t)B_IMGS * NSEL * 16;
static constexpr size_t OFF_BOXL  = OFF_SCR  + (size_t)B_IMGS * NSEL * 4;
static constexpr size_t OFF_VAL   = OFF_BOXL + (size_t)B_IMGS * NSEL * 16;
static constexpr size_t OFF_RMAP  = OFF_VAL  + (size_t)B_IMGS * NSEL * 4;
static constexpr size_t OFF_KEEP  = OFF_RMAP + (size_t)B_IMGS * NSEL * 4;
static constexpr size_t OFF_MASK  = (OFF_KEEP + (size_t)B_IMGS * NSEL * 4 + 15) & ~(size_t)15;
static constexpr size_t WS_NEED   = OFF_MASK + (size_t)NBL * 1024 * 16 * 8;   // ~8.5 MB

// ---------- K1: per-span LDS histogram -> private global slice (no atomics) ----------
// 34 blocks/image, 512 threads. l4 block zeroes cnt[20]+di[4]+d2[4] instead.
#define HBLK_PER_IMG 34
__global__ __launch_bounds__(512) void k_hist(const float* __restrict__ obj,
                                              unsigned* __restrict__ hist_sl,
                                              unsigned* __restrict__ part_sl,
                                              unsigned* __restrict__ cntz) {
    __shared__ __align__(16) unsigned lh[NBUCK];   // 32 KB
    const int tid = threadIdx.x;     // 512
    const int b = blockIdx.x / HBLK_PER_IMG;
    const int r = blockIdx.x - b * HBLK_PER_IMG;
    if (r == 33) {                   // l4 block: zero cnt[20]+di[4]+d2[4]
        if (b == 0 && tid < 28) cntz[tid] = 0;
        return;
    }
    int sofs, sub, chunk, lstart, n;
    if (r < 24)      { sofs = 0;  sub = r;      chunk = 7600; lstart = 0;      n = 182400; }
    else if (r < 30) { sofs = 24; sub = r - 24; chunk = 7600; lstart = 182400; n = 45600; }
    else if (r < 32) { sofs = 30; sub = r - 30; chunk = 5700; lstart = 228000; n = 11400; }
    else             { sofs = 32; sub = 0;      chunk = 2850; lstart = 239400; n = 2850; }
    #pragma unroll
    for (int i = tid; i < NBUCK; i += 512) lh[i] = 0;
    __syncthreads();
    const int s0 = sub * chunk;
    const int m = min(chunk, n - s0);
    const float* src = obj + (size_t)b * A_TOTAL + lstart + s0;
    // vectorized histogram (float4 + 4-deep unroll; peel to 16B alignment)
    const int peel0 = (int)(((16u - ((unsigned)(uintptr_t)src & 15u)) & 15u) >> 2);
    const int peel  = (peel0 < m) ? peel0 : m;
    const int nv    = (m - peel) >> 2;
    const float4* s4 = (const float4*)(src + peel);
    const int tail0 = peel + (nv << 2);
#define H1(f) atomicAdd(&lh[flipf(f) >> BSHIFT], 1u)
#define H4(v) do { H1((v).x); H1((v).y); H1((v).z); H1((v).w); } while (0)
    if (tid < peel) H1(src[tid]);
    for (int i = tid; i < nv; i += 2048) {
        if (i + 1536 < nv) {
            float4 a0 = s4[i], a1 = s4[i + 512], a2 = s4[i + 1024], a3 = s4[i + 1536];
            H4(a0); H4(a1); H4(a2); H4(a3);
        } else {
            float4 a0 = s4[i]; H4(a0);
            if (i + 512  < nv) { float4 a = s4[i + 512];  H4(a); }
            if (i + 1024 < nv) { float4 a = s4[i + 1024]; H4(a); }
        }
    }
    for (int i = tail0 + tid; i < m; i += 512) H1(src[i]);
#undef H4
#undef H1
    __syncthreads();
    const int slice = b * NSLICE_PER_IMG + sofs + sub;
    unsigned* gh = hist_sl + (size_t)slice * NBUCK;
    #pragma unroll
    for (int i = tid; i < NBUCK / 4; i += 512)
        ((uint4*)gh)[i] = ((const uint4*)lh)[i];
    if (tid < 256) {
        unsigned s = 0;
        #pragma unroll
        for (int i = 0; i < 32; ++i) s += lh[tid * 32 + ((i + tid) & 31)];
        part_sl[(size_t)slice * 256 + tid] = s;
    }
}

// ---------- K2: threshold (from slice sums) + vectorized compact ----------
#define CBLK_PER_IMG 65
__global__ __launch_bounds__(256) void k_compact(const float* __restrict__ obj,
                                                 const unsigned* __restrict__ hist_sl,
                                                 const unsigned* __restrict__ part_sl,
                                                 unsigned* __restrict__ cnt,
                                                 unsigned long long* __restrict__ cand) {
    __shared__ unsigned long long sbuf[CAND_CAP];   // 16 KB staging
    __shared__ unsigned wsum[4];
    __shared__ unsigned fcnt[4];
    __shared__ unsigned s_cum, s_thr, lcnt, gbase;
    const int tid = threadIdx.x;     // 256
    const int b = blockIdx.x / CBLK_PER_IMG;
    const int r = blockIdx.x - b * CBLK_PER_IMG;
    int l, sofs, nsub, sub, chunk, lstart, n;
    if (r < 48)      { l = 0; sofs = 0;  nsub = 24; sub = r;      chunk = 3800; lstart = 0;      n = 182400; }
    else if (r < 60) { l = 1; sofs = 24; nsub = 6;  sub = r - 48; chunk = 3800; lstart = 182400; n = 45600; }
    else if (r < 63) { l = 2; sofs = 30; nsub = 2;  sub = r - 60; chunk = 3800; lstart = 228000; n = 11400; }
    else if (r == 63){ l = 3; sofs = 32; nsub = 1;  sub = 0;      chunk = 2850; lstart = 239400; n = 2850; }
    else             { l = 4; sofs = 33; nsub = 0;  sub = 0;      chunk = 741;  lstart = 242250; n = 741; }
    const int bl = b * NLVL + l;
    const int kl = lvl_k(l);
    if (tid == 0) { lcnt = 0; s_cum = 0; }
    __syncthreads();
    unsigned T = 0;
    if (l < 4) {   // l4: n <= k -> every element passes, T = 0
        const int lane = tid & 63, wv = tid >> 6;
        // stage 1: suffix(t) over 256 chunk-sums (t = 255 - tid)
        const unsigned* pb = part_sl + (size_t)(b * NSLICE_PER_IMG + sofs) * 256 + (255 - tid);
        unsigned x = 0;
        #pragma unroll 6
        for (int s = 0; s < nsub; ++s) x += pb[(size_t)s * 256];
        #pragma unroll
        for (int d = 1; d < 64; d <<= 1) {
            unsigned up = __shfl_up(x, d);
            if (lane >= d) x += up;
        }
        if (lane == 63) wsum[wv] = x;
        __syncthreads();
        unsigned add = 0;
        #pragma unroll
        for (int u = 0; u < 3; ++u) if (u < wv) add += wsum[u];
        const unsigned suffix = x + add;                 // suffix(255 - tid)
        unsigned long long bm = __ballot(suffix >= (unsigned)kl);
        if (lane == 0) fcnt[wv] = (unsigned)__popcll(bm);
        __syncthreads();
        const int chnk = (int)(fcnt[0] + fcnt[1] + fcnt[2] + fcnt[3]) - 1;
        if ((255 - tid) == chnk + 1) s_cum = suffix;     // 0 if chnk==255
        __syncthreads();
        // stage 2 (wave 0): largest bucket in chunk with suffix >= kl
        if (tid < 64) {
            unsigned y = 0;
            if (tid < 32) {
                const unsigned* hb = hist_sl + (size_t)(b * NSLICE_PER_IMG + sofs) * NBUCK
                                   + chnk * 32 + (31 - tid);
                #pragma unroll 6
                for (int s = 0; s < nsub; ++s) y += hb[(size_t)s * NBUCK];
            }
            #pragma unroll
            for (int d = 1; d < 32; d <<= 1) {
                unsigned up = __shfl_up(y, d);
                if (tid >= d) y += up;
            }
            unsigned suf2 = s_cum + y;                   // bucket i = 31 - tid
            unsigned long long bm2 = __ballot((tid < 32) && (suf2 >= (unsigned)kl));
            if (tid == 0) {
                int istar = (int)__popcll(bm2) - 1;
                s_thr = (unsigned)(chnk * 32 + istar);
            }
        }
        __syncthreads();
        T = s_thr;
    }
    // ---- vectorized pass filter into LDS staging ----
    const int s0 = sub * chunk;
    const int m = min(chunk, n - s0);
    const int abase = lstart + s0;
    const float* src = obj + (size_t)b * A_TOTAL + abase;
    const int peel0 = (int)(((16u - ((unsigned)(uintptr_t)src & 15u)) & 15u) >> 2);
    const int peel  = (peel0 < m) ? peel0 : m;
    const int nv    = (m - peel) >> 2;
    const float4* s4 = (const float4*)(src + peel);
    const int tail0 = peel + (nv << 2);
#define E1(f, idx) do { unsigned os_ = flipf(f); \
    if ((os_ >> BSHIFT) >= T) { \
        unsigned slot = atomicAdd(&lcnt, 1u); \
        if (slot < CAND_CAP) \
            sbuf[slot] = (((unsigned long long)(~os_)) << 32) | (unsigned)(idx); \
    } } while (0)
#define E4(v, gb) do { E1((v).x, (gb)); E1((v).y, (gb) + 1); \
                       E1((v).z, (gb) + 2); E1((v).w, (gb) + 3); } while (0)
    if (tid < peel) E1(src[tid], abase + tid);
    for (int i = tid; i < nv; i += 512) {
        const int gb0 = abase + peel + (i << 2);
        if (i + 256 < nv) {
            float4 a0 = s4[i], a1 = s4[i + 256];
            E4(a0, gb0);
            E4(a1, gb0 + 1024);
        } else {
            float4 a0 = s4[i];
            E4(a0, gb0);
        }
    }
    for (int i = tail0 + tid; i < m; i += 256) E1(src[i], abase + i);
#undef E4
#undef E1
    __syncthreads();
    unsigned total = lcnt; if (total > CAND_CAP) total = CAND_CAP;
    if (tid == 0) gbase = atomicAdd(&cnt[bl], total);
    __syncthreads();
    const unsigned gb = gbase;
    for (unsigned i = tid; i < total; i += 256) {
        unsigned g = gb + i;
        if (g < CAND_CAP)
            cand[(size_t)bl * CAND_CAP + g] = sbuf[i];
    }
}

// ---------- binary search in LDS: #elements < key ----------
__device__ __forceinline__ int lbound_lds(const unsigned long long* s, int len,
                                          unsigned long long key) {
    int lo = 0, hi = len;
    while (lo < hi) {
        int mid = (lo + hi) >> 1;
        if (s[mid] < key) lo = mid + 1; else hi = mid;
    }
    return lo;
}

// ---------- K3: per-(b,level) bitonic sort + per-image barrier + PARALLEL decode ----------
// 20 blocks x 1024. Sort body verbatim (R7). Then a per-image 5-block spin
// barrier (20 releases total). After the barrier ALL 5 blocks of the image
// decode their own sub-range (sub = l, R7's blockIdx.x mapping).
__global__ __launch_bounds__(1024) void k_sortdec(
        const unsigned long long* __restrict__ cand, const unsigned* __restrict__ cnt,
        unsigned long long* __restrict__ sel,
        const float* __restrict__ deltas, const float* __restrict__ anchors,
        float* __restrict__ boxes_r, float* __restrict__ score_r,
        float* __restrict__ boxes_l, int* __restrict__ valid_l,
        int* __restrict__ rankmap, unsigned* __restrict__ boxmax5,
        unsigned* __restrict__ bar_i) {
    __shared__ __align__(16) char smem[38016];   // sort keys 16K | decode skey 37,928
    __shared__ float wmax[16];
    const int bl = blockIdx.x;
    const int b = bl / NLVL, l = bl - (bl / NLVL) * NLVL;
    const int tid = threadIdx.x;     // 1024

    // ---- sort phase (R7 k_sort body) ----
    {
        unsigned long long* keys = (unsigned long long*)smem;
        int m = (int)cnt[bl];
        if (m > CAND_CAP) m = CAND_CAP;
        for (int i = tid; i < CAND_CAP; i += 1024)
            keys[i] = (i < m) ? cand[(size_t)bl * CAND_CAP + i] : ~0ULL;
        __syncthreads();
        for (int k = 2; k <= CAND_CAP; k <<= 1) {
            for (int j = k >> 1; j > 0; j >>= 1) {
                int i = ((tid / j) * (j << 1)) + (tid % j);
                int p = i + j;
                bool up = ((i & k) == 0);
                unsigned long long a = keys[i], c = keys[p];
                if ((a > c) == up) { keys[i] = c; keys[p] = a; }
                __syncthreads();
            }
        }
        int kl = lvl_k(l);
        for (int q = tid; q < kl; q += 1024)
            sel[(size_t)b * NSEL + l * 1000 + q] = keys[q];
    }
    __syncthreads();   // drain sel stores (vmcnt) before release

    // ---- per-image 5-block spin barrier (all blocks proceed) ----
    if (tid == 0) {
        __threadfence();   // agent release: this block's sel visible
        __hip_atomic_fetch_add(bar_i + b, 1u, __ATOMIC_RELAXED, __HIP_MEMORY_SCOPE_AGENT);
        while (__hip_atomic_load(bar_i + b, __ATOMIC_RELAXED, __HIP_MEMORY_SCOPE_AGENT)
               < (unsigned)NLVL)
            __builtin_amdgcn_s_sleep(2);
        __threadfence();   // agent acquire: all 5 levels' sel visible
    }
    __syncthreads();

    // ---- decode phase (R7 k_decode body; sub = l, full 20-block parallelism) ----
    unsigned long long* skey = (unsigned long long*)smem;
    for (int i = tid; i < NSEL; i += 1024)
        skey[i] = sel[(size_t)b * NSEL + i];
    __syncthreads();
    const int sub = l;
    int p = sub * 1024 + tid;
    bool on = p < NSEL;
    float mx = 0.0f;
    if (on) {
        int l2i = p / 1000;         // p in [4000,4741) -> 4
        int q = p - l2i * 1000;
        unsigned long long key = skey[p];
        unsigned a = (unsigned)(key & 0xFFFFFFFFu);
        unsigned os = ~((unsigned)(key >> 32));
        if (a >= A_TOTAL) a = 0;    // impossible-path safety (MAX padding)
        float score = unflipf(os);
        int r = q;
        for (int l2 = 0; l2 < NLVL; ++l2) {
            if (l2 == l2i) continue;
            r += lbound_lds(skey + l2 * 1000, lvl_k(l2), key);
        }
        const float* dv = deltas + ((size_t)b * A_TOTAL + a) * 4;
        const float* av = anchors + (size_t)a * 4;
        float ax1 = av[0], ay1 = av[1], ax2 = av[2], ay2 = av[3];
        float wa = ax2 - ax1, ha = ay2 - ay1;
        float cxa = ax1 + 0.5f * wa, cya = ay1 + 0.5f * ha;
        float dx = dv[0], dy = dv[1];
        float dw = fminf(dv[2], BBOX_CLIP), dh = fminf(dv[3], BBOX_CLIP);
        float cx = dx * wa + cxa, cy = dy * ha + cya;
        float w = expf(dw) * wa, h = expf(dh) * ha;
        float x1 = cx - 0.5f * w, y1 = cy - 0.5f * h;
        float x2 = cx + 0.5f * w, y2 = cy + 0.5f * h;
        float x1c = fminf(fmaxf(x1, 0.0f), W_IMGF);
        float y1c = fminf(fmaxf(y1, 0.0f), H_IMGF);
        float x2c = fminf(fmaxf(x2, 0.0f), W_IMGF);
        float y2c = fminf(fmaxf(y2, 0.0f), H_IMGF);
        int valid = ((x2c - x1c) >= MIN_SZ) && ((y2c - y1c) >= MIN_SZ);
        mx = fmaxf(fmaxf(x1c, y1c), fmaxf(x2c, y2c));
        size_t rp = (size_t)b * NSEL + r;
        boxes_r[rp * 4 + 0] = x1c; boxes_r[rp * 4 + 1] = y1c;
        boxes_r[rp * 4 + 2] = x2c; boxes_r[rp * 4 + 3] = y2c;
        score_r[rp] = score;
        size_t pp = (size_t)b * NSEL + p;
        boxes_l[pp * 4 + 0] = x1c; boxes_l[pp * 4 + 1] = y1c;
        boxes_l[pp * 4 + 2] = x2c; boxes_l[pp * 4 + 3] = y2c;
        valid_l[pp] = valid;
        rankmap[pp] = r;
    }
    // block max reduction -> private slot (coords >= 0; fmax exact/orderless)
    #pragma unroll
    for (int o = 32; o > 0; o >>= 1)
        mx = fmaxf(mx, __shfl_xor(mx, o));
    if ((tid & 63) == 0) wmax[tid >> 6] = mx;
    __syncthreads();
    if (tid == 0) {
        float m2 = wmax[0];
        #pragma unroll
        for (int i = 1; i < 16; ++i) m2 = fmaxf(m2, wmax[i]);
        boxmax5[b * 5 + sub] = __float_as_uint(m2);
    }
}

// ---------- K4: suppression bitmask (full grid, R7 body; max-of-5 boxmax) ----------
__global__ void k_mask(const float* __restrict__ boxes_l, const unsigned* __restrict__ boxmax5,
                       unsigned long long* __restrict__ mask) {
    int bl = blockIdx.z;
    int b = bl / NLVL, l = bl - b * NLVL;
    int kl = lvl_k(l);
    int w = blockIdx.x, rg = blockIdx.y, tid = threadIdx.x;
    if (rg * 256 >= kl) return;
    float M = __uint_as_float(boxmax5[b * 5 + 0]);
    #pragma unroll
    for (int j = 1; j < 5; ++j) M = fmaxf(M, __uint_as_float(boxmax5[b * 5 + j]));
    M += 1.0f;
    float off = (float)l * M;
    __shared__ float cb[64][5];
    int j0 = w * 64;
    if (tid < 64) {
        int j = j0 + tid;
        if (j < kl) {
            const float* bp = boxes_l + ((size_t)b * NSEL + l * 1000 + j) * 4;
            float x1 = bp[0] + off, y1 = bp[1] + off, x2 = bp[2] + off, y2 = bp[3] + off;
            cb[tid][0] = x1; cb[tid][1] = y1; cb[tid][2] = x2; cb[tid][3] = y2;
            cb[tid][4] = (x2 - x1) * (y2 - y1);
        }
    }
    __syncthreads();
    int i = rg * 256 + tid;
    if (i >= kl) return;
    unsigned long long word = 0;
    if (j0 + 63 > i) {
        const float* bp = boxes_l + ((size_t)b * NSEL + l * 1000 + i) * 4;
        float ix1 = bp[0] + off, iy1 = bp[1] + off, ix2 = bp[2] + off, iy2 = bp[3] + off;
        float ai = (ix2 - ix1) * (iy2 - iy1);
        int jmax = min(64, kl - j0);
        for (int bb = 0; bb < jmax; ++bb) {
            int jj = j0 + bb;
            if (jj <= i) continue;
            float ltx = fmaxf(ix1, cb[bb][0]), lty = fmaxf(iy1, cb[bb][1]);
            float rbx = fminf(ix2, cb[bb][2]), rby = fminf(iy2, cb[bb][3]);
            float ww = fmaxf(rbx - ltx, 0.0f), hh = fmaxf(rby - lty, 0.0f);
            float inter = ww * hh;
            float iou = inter / ((ai + cb[bb][4]) - inter);   // NaN>th == false, matches jnp
            if (iou > NMS_TH) word |= (1ULL << bb);
        }
    }
    mask[((size_t)bl * 1024 + i) * 16 + w] = word;
}

// ---------- K5: resolve (whole mask slice prefetched to LDS) + last-of-image output ----------
// 20 blocks x 256. Wave 0 issues ALL chunk DMAs upfront (<=128 KB fits gfx950's
// 160 KB LDS; vmcnt throttling >63 outstanding just stalls issue — harmless),
// one barrier drains, then the serial greedy loop runs barrier-free from LDS.
// Resolve logic, scatter, done2 epilogue and output body verbatim from R11.
__global__ __launch_bounds__(256) void k_resout(const int* __restrict__ valid_l,
                                                const int* __restrict__ rankmap,
                                                const unsigned long long* __restrict__ mask,
                                                int* __restrict__ keep_r,
                                                unsigned* __restrict__ done2,
                                                const float* __restrict__ boxes_r,
                                                const float* __restrict__ score_r,
                                                float* __restrict__ out) {
    __shared__ __align__(16) unsigned long long sb[16 * 1024];   // 128 KB: all chunks
    __shared__ int ps[256];
    __shared__ int s_flag;
    const int bl = blockIdx.x;
    const int b = bl / NLVL, l = bl - b * NLVL;
    const int kl = lvl_k(l);
    const int tid = threadIdx.x;     // 256
    const int lane = tid & 63;
    const int base = b * NSEL + l * 1000;
    const int nch = (kl + 63) >> 6;   // 16 or 12
    const char* mbyte = (const char*)(mask + (size_t)bl * 1024 * 16);

    unsigned long long keep_w = 0;
    if (tid < 64) {
        // issue ALL chunk DMAs upfront (nch*8 x 1KB instructions)
        for (int c = 0; c < nch; ++c) {
            const char* g = mbyte + (size_t)c * 8192 + (size_t)lane * 16;
            char* d = (char*)sb + (size_t)c * 8192;
            #pragma unroll
            for (int j = 0; j < 8; ++j)
                async_cp16(g + j * 1024, d + j * 1024);
        }
        // keep word per chunk, distributed: lane w (w<16) holds chunk w's bits
        for (int c = 0; c < 16; ++c) {
            int q = c * 64 + lane;
            int vv = (q < kl) ? valid_l[base + q] : 0;
            unsigned long long bm = __ballot(vv);
            if (lane == c) keep_w = bm;
        }
    }
    __syncthreads();                 // drains wave0 vmcnt: entire mask slice staged

    if (tid < 64) {
        for (int c = 0; c < nch; ++c) {
            unsigned long long* cur = sb + (size_t)c * 1024;
            unsigned long long kw = __shfl(keep_w, c);   // uniform in wave
            if (kw) {
                // diagonal word (word c of this lane's row)
                unsigned long long diag = cur[lane * 16 + c];
                unsigned dlo = (unsigned)diag, dhi = (unsigned)(diag >> 32);
                unsigned long long nz = __ballot(diag != 0ULL);
                unsigned long long rem = kw & nz;
                while (rem) {
                    int rr = __ffsll((long long)rem) - 1;
                    unsigned lo = __builtin_amdgcn_readlane(dlo, rr);
                    unsigned hi = __builtin_amdgcn_readlane(dhi, rr);
                    unsigned long long d = ((unsigned long long)hi << 32) | lo;
                    kw &= ~d;
                    rem &= ~(d | (1ULL << rr));
                }
                // batched cross-chunk suppression: lane w<16 ORs word w of kept rows
                unsigned long long supp = 0;
                if (lane < 16) {
                    #pragma unroll
                    for (int rr = 0; rr < 64; ++rr) {
                        unsigned long long mm = cur[rr * 16 + lane];
                        supp |= (((kw >> rr) & 1ULL) ? mm : 0ULL);
                    }
                }
                if (lane == c) keep_w = kw;
                else if (lane < 16 && lane > c) keep_w &= ~supp;
            }
        }
        // scatter keep bits to global-rank order
        for (int c = 0; c < 16; ++c) {
            unsigned long long kwc = __shfl(keep_w, c);
            int q = c * 64 + lane;
            if (q < kl)
                keep_r[b * NSEL + rankmap[base + q]] = (int)((kwc >> lane) & 1ULL);
        }
    }
    __syncthreads();   // drain keep_r stores before release

    // ---- last-of-image output epilogue (20 releases total) ----
    if (tid == 0) {
        __threadfence();   // agent release: keep_r visible
        unsigned old = __hip_atomic_fetch_add(done2 + b, 1u,
                                              __ATOMIC_ACQ_REL, __HIP_MEMORY_SCOPE_AGENT);
        s_flag = (old == NLVL - 1);
        if (old == NLVL - 1) __threadfence();   // agent acquire
    }
    __syncthreads();
    if (!s_flag) return;

    // verified 256-thread output body (CH=19: 19*256 = 4864 >= 4741)
    float* ob = out + (size_t)b * POST_NMS * 4;
    float* osc = out + (size_t)B_IMGS * POST_NMS * 4 + (size_t)b * POST_NMS;
    for (int p = tid; p < POST_NMS; p += 256) {
        ob[p * 4 + 0] = 0.0f; ob[p * 4 + 1] = 0.0f;
        ob[p * 4 + 2] = 0.0f; ob[p * 4 + 3] = 0.0f;
        osc[p] = NEGV;
    }
    __syncthreads();
    const int CH = 19;
    int basei = tid * CH;
    int c0 = 0;
    #pragma unroll
    for (int k = 0; k < CH; ++k) {
        int rr = basei + k;
        if (rr < NSEL) c0 += keep_r[b * NSEL + rr];
    }
    ps[tid] = c0;
    __syncthreads();
    for (int ofs = 1; ofs < 256; ofs <<= 1) {
        int v = (tid >= ofs) ? ps[tid - ofs] : 0;
        __syncthreads();
        ps[tid] += v;
        __syncthreads();
    }
    int p = ps[tid] - c0;   // exclusive prefix
    #pragma unroll
    for (int k = 0; k < CH; ++k) {
        int rr = basei + k;
        if (rr < NSEL && keep_r[b * NSEL + rr]) {
            if (p < POST_NMS) {
                const float* bp = boxes_r + ((size_t)b * NSEL + rr) * 4;
                ob[p * 4 + 0] = bp[0]; ob[p * 4 + 1] = bp[1];
                ob[p * 4 + 2] = bp[2]; ob[p * 4 + 3] = bp[3];
                osc[p] = score_r[(size_t)b * NSEL + rr];
            }
            ++p;
        }
    }
}

extern "C" void kernel_launch(void* const* d_in, const int* in_sizes, int n_in,
                              void* d_out, int out_size, void* d_ws, size_t ws_size,
                              hipStream_t stream) {
    const float* obj     = (const float*)d_in[0];   // [4, 242991]
    const float* deltas  = (const float*)d_in[1];   // [4, 242991, 4]
    const float* anchors = (const float*)d_in[2];   // [242991, 4]
    float* out = (float*)d_out;                     // [4,1000,4] ++ [4,1000]

    char* ws = (char*)d_ws;
    unsigned*            boxmax5 = (unsigned*)(ws + OFF_BM5);
    unsigned*            cnt     = (unsigned*)(ws + OFF_CNT);
    unsigned*            bar_i   = (unsigned*)(ws + OFF_DI);
    unsigned*            done2   = (unsigned*)(ws + OFF_D2);
    unsigned*            hist_sl = (unsigned*)(ws + OFF_HSL);
    unsigned*            part_sl = (unsigned*)(ws + OFF_PSL);
    unsigned long long*  cand    = (unsigned long long*)(ws + OFF_CAND);
    unsigned long long*  sel     = (unsigned long long*)(ws + OFF_SEL);
    float*               boxes_r = (float*)(ws + OFF_BOXR);
    float*               score_r = (float*)(ws + OFF_SCR);
    float*               boxes_l = (float*)(ws + OFF_BOXL);
    int*                 valid_l = (int*)(ws + OFF_VAL);
    int*                 rankmap = (int*)(ws + OFF_RMAP);
    int*                 keep_r  = (int*)(ws + OFF_KEEP);
    unsigned long long*  maskp   = (unsigned long long*)(ws + OFF_MASK);

    (void)in_sizes; (void)n_in; (void)out_size; (void)ws_size; (void)WS_NEED;

    // No memset: hist/part slices are plain-store overwritten; cnt+bar_i+done2
    // zeroed by k_hist's l4 block (kernel-boundary visibility); boxmax5 is
    // plain-stored by k_sortdec; keep_r fully written before any read.
    k_hist<<<B_IMGS * HBLK_PER_IMG, 512, 0, stream>>>(obj, hist_sl, part_sl, cnt);
    k_compact<<<B_IMGS * CBLK_PER_IMG, 256, 0, stream>>>(obj, hist_sl, part_sl, cnt, cand);
    k_sortdec<<<NBL, 1024, 0, stream>>>(cand, cnt, sel, deltas, anchors,
                                        boxes_r, score_r, boxes_l, valid_l,
                                        rankmap, boxmax5, bar_i);
    k_mask<<<dim3(16, 4, NBL), 256, 0, stream>>>(boxes_l, boxmax5, maskp);
    k_resout<<<NBL, 256, 0, stream>>>(valid_l, rankmap, maskp, keep_r, done2,
                                      boxes_r, score_r, out);
}

// Round 13
// 176.809 us; speedup vs baseline: 1.7961x; 1.0144x over previous
//
#include <hip/hip_runtime.h>
#include <stdint.h>

// Disable FMA contraction file-wide: we must replicate the reference's
// per-op f32 rounding (decode + IoU) to avoid NMS decision flips.
#pragma clang fp contract(off)

#define B_IMGS   4
#define NLVL     5
#define A_TOTAL  242991
#define NSEL     4741          // 1000*4 + 741
#define NBUCK    8192          // 13-bit buckets: sign+exp+4 mantissa (os>>19)
#define BSHIFT   19
#define CAND_CAP 2048
#define POST_NMS 1000
#define NBL      (B_IMGS * NLVL)
#define NMS_TH   0.7f
#define NEGV     (-1e10f)
#define W_IMGF   1216.0f
#define H_IMGF   800.0f
#define MIN_SZ   1e-3f
#define BBOX_CLIP 4.135166556742356f   // log(1000/16), rounded to f32 by compiler

#define NSLICE_PER_IMG 34      // hist slices per image (l0:24 l1:6 l2:2 l3:1 l4:1-unused)

// ---------- level helpers ----------
__device__ __forceinline__ int lvl_k(int l) { return (l == 4) ? 741 : 1000; }

// ---------- order-preserving float<->uint ----------
__device__ __forceinline__ unsigned flipf(float f) {
    unsigned u = __float_as_uint(f);
    return u ^ (unsigned)(((int)u >> 31) | 0x80000000);
}
__device__ __forceinline__ float unflipf(unsigned os) {
    unsigned u = (os & 0x80000000u) ? (os ^ 0x80000000u) : ~os;
    return __uint_as_float(u);
}

// ---------- workspace layout (NOTHING pre-zeroed; counters zeroed by k_hist) ----------
static constexpr size_t OFF_BM5   = 0;                                        // u32[20]
static constexpr size_t OFF_CNT   = 128;                                      // u32[20]
static constexpr size_t OFF_DI    = 208;                                      // u32[4] sortdec barrier
static constexpr size_t OFF_D2    = 224;                                      // u32[4] resout done
static constexpr size_t OFF_HSL   = 256;                                      // u32[4*34*8192]
static constexpr size_t OFF_PSL   = OFF_HSL  + (size_t)B_IMGS * NSLICE_PER_IMG * NBUCK * 4;
static constexpr size_t OFF_CAND  = OFF_PSL  + (size_t)B_IMGS * NSLICE_PER_IMG * 256 * 4;
static constexpr size_t OFF_SEL   = OFF_CAND + (size_t)NBL * CAND_CAP * 8;
static constexpr size_t OFF_BOXR  = OFF_SEL  + (size_t)B_IMGS * NSEL * 8;
static constexpr size_t OFF_SCR   = OFF_BOXR + (size_t)B_IMGS * NSEL * 16;
static constexpr size_t OFF_BOXL  = OFF_SCR  + (size_t)B_IMGS * NSEL * 4;
static constexpr size_t OFF_VAL   = OFF_BOXL + (size_t)B_IMGS * NSEL * 16;
static constexpr size_t OFF_RMAP  = OFF_VAL  + (size_t)B_IMGS * NSEL * 4;
static constexpr size_t OFF_KEEP  = OFF_RMAP + (size_t)B_IMGS * NSEL * 4;
static constexpr size_t OFF_MASK  = (OFF_KEEP + (size_t)B_IMGS * NSEL * 4 + 15) & ~(size_t)15;
static constexpr size_t WS_NEED   = OFF_MASK + (size_t)NBL * 1024 * 16 * 8;   // ~8.5 MB

// ---------- K1: per-span LDS histogram -> private global slice (no atomics) ----------
// 34 blocks/image, 512 threads. l4 block zeroes cnt[20]+di[4]+d2[4] instead.
#define HBLK_PER_IMG 34
__global__ __launch_bounds__(512) void k_hist(const float* __restrict__ obj,
                                              unsigned* __restrict__ hist_sl,
                                              unsigned* __restrict__ part_sl,
                                              unsigned* __restrict__ cntz) {
    __shared__ __align__(16) unsigned lh[NBUCK];   // 32 KB
    const int tid = threadIdx.x;     // 512
    const int b = blockIdx.x / HBLK_PER_IMG;
    const int r = blockIdx.x - b * HBLK_PER_IMG;
    if (r == 33) {                   // l4 block: zero cnt[20]+di[4]+d2[4]
        if (b == 0 && tid < 28) cntz[tid] = 0;
        return;
    }
    int sofs, sub, chunk, lstart, n;
    if (r < 24)      { sofs = 0;  sub = r;      chunk = 7600; lstart = 0;      n = 182400; }
    else if (r < 30) { sofs = 24; sub = r - 24; chunk = 7600; lstart = 182400; n = 45600; }
    else if (r < 32) { sofs = 30; sub = r - 30; chunk = 5700; lstart = 228000; n = 11400; }
    else             { sofs = 32; sub = 0;      chunk = 2850; lstart = 239400; n = 2850; }
    #pragma unroll
    for (int i = tid; i < NBUCK; i += 512) lh[i] = 0;
    __syncthreads();
    const int s0 = sub * chunk;
    const int m = min(chunk, n - s0);
    const float* src = obj + (size_t)b * A_TOTAL + lstart + s0;
    // vectorized histogram (float4 + 4-deep unroll; peel to 16B alignment)
    const int peel0 = (int)(((16u - ((unsigned)(uintptr_t)src & 15u)) & 15u) >> 2);
    const int peel  = (peel0 < m) ? peel0 : m;
    const int nv    = (m - peel) >> 2;
    const float4* s4 = (const float4*)(src + peel);
    const int tail0 = peel + (nv << 2);
#define H1(f) atomicAdd(&lh[flipf(f) >> BSHIFT], 1u)
#define H4(v) do { H1((v).x); H1((v).y); H1((v).z); H1((v).w); } while (0)
    if (tid < peel) H1(src[tid]);
    for (int i = tid; i < nv; i += 2048) {
        if (i + 1536 < nv) {
            float4 a0 = s4[i], a1 = s4[i + 512], a2 = s4[i + 1024], a3 = s4[i + 1536];
            H4(a0); H4(a1); H4(a2); H4(a3);
        } else {
            float4 a0 = s4[i]; H4(a0);
            if (i + 512  < nv) { float4 a = s4[i + 512];  H4(a); }
            if (i + 1024 < nv) { float4 a = s4[i + 1024]; H4(a); }
        }
    }
    for (int i = tail0 + tid; i < m; i += 512) H1(src[i]);
#undef H4
#undef H1
    __syncthreads();
    const int slice = b * NSLICE_PER_IMG + sofs + sub;
    unsigned* gh = hist_sl + (size_t)slice * NBUCK;
    #pragma unroll
    for (int i = tid; i < NBUCK / 4; i += 512)
        ((uint4*)gh)[i] = ((const uint4*)lh)[i];
    if (tid < 256) {
        unsigned s = 0;
        #pragma unroll
        for (int i = 0; i < 32; ++i) s += lh[tid * 32 + ((i + tid) & 31)];
        part_sl[(size_t)slice * 256 + tid] = s;
    }
}

// ---------- K2: threshold (from slice sums) + vectorized compact ----------
#define CBLK_PER_IMG 65
__global__ __launch_bounds__(256) void k_compact(const float* __restrict__ obj,
                                                 const unsigned* __restrict__ hist_sl,
                                                 const unsigned* __restrict__ part_sl,
                                                 unsigned* __restrict__ cnt,
                                                 unsigned long long* __restrict__ cand) {
    __shared__ unsigned long long sbuf[CAND_CAP];   // 16 KB staging
    __shared__ unsigned wsum[4];
    __shared__ unsigned fcnt[4];
    __shared__ unsigned s_cum, s_thr, lcnt, gbase;
    const int tid = threadIdx.x;     // 256
    const int b = blockIdx.x / CBLK_PER_IMG;
    const int r = blockIdx.x - b * CBLK_PER_IMG;
    int l, sofs, nsub, sub, chunk, lstart, n;
    if (r < 48)      { l = 0; sofs = 0;  nsub = 24; sub = r;      chunk = 3800; lstart = 0;      n = 182400; }
    else if (r < 60) { l = 1; sofs = 24; nsub = 6;  sub = r - 48; chunk = 3800; lstart = 182400; n = 45600; }
    else if (r < 63) { l = 2; sofs = 30; nsub = 2;  sub = r - 60; chunk = 3800; lstart = 228000; n = 11400; }
    else if (r == 63){ l = 3; sofs = 32; nsub = 1;  sub = 0;      chunk = 2850; lstart = 239400; n = 2850; }
    else             { l = 4; sofs = 33; nsub = 0;  sub = 0;      chunk = 741;  lstart = 242250; n = 741; }
    const int bl = b * NLVL + l;
    const int kl = lvl_k(l);
    if (tid == 0) { lcnt = 0; s_cum = 0; }
    __syncthreads();
    unsigned T = 0;
    if (l < 4) {   // l4: n <= k -> every element passes, T = 0
        const int lane = tid & 63, wv = tid >> 6;
        // stage 1: suffix(t) over 256 chunk-sums (t = 255 - tid)
        const unsigned* pb = part_sl + (size_t)(b * NSLICE_PER_IMG + sofs) * 256 + (255 - tid);
        unsigned x = 0;
        #pragma unroll 6
        for (int s = 0; s < nsub; ++s) x += pb[(size_t)s * 256];
        #pragma unroll
        for (int d = 1; d < 64; d <<= 1) {
            unsigned up = __shfl_up(x, d);
            if (lane >= d) x += up;
        }
        if (lane == 63) wsum[wv] = x;
        __syncthreads();
        unsigned add = 0;
        #pragma unroll
        for (int u = 0; u < 3; ++u) if (u < wv) add += wsum[u];
        const unsigned suffix = x + add;                 // suffix(255 - tid)
        unsigned long long bm = __ballot(suffix >= (unsigned)kl);
        if (lane == 0) fcnt[wv] = (unsigned)__popcll(bm);
        __syncthreads();
        const int chnk = (int)(fcnt[0] + fcnt[1] + fcnt[2] + fcnt[3]) - 1;
        if ((255 - tid) == chnk + 1) s_cum = suffix;     // 0 if chnk==255
        __syncthreads();
        // stage 2 (wave 0): largest bucket in chunk with suffix >= kl
        if (tid < 64) {
            unsigned y = 0;
            if (tid < 32) {
                const unsigned* hb = hist_sl + (size_t)(b * NSLICE_PER_IMG + sofs) * NBUCK
                                   + chnk * 32 + (31 - tid);
                #pragma unroll 6
                for (int s = 0; s < nsub; ++s) y += hb[(size_t)s * NBUCK];
            }
            #pragma unroll
            for (int d = 1; d < 32; d <<= 1) {
                unsigned up = __shfl_up(y, d);
                if (tid >= d) y += up;
            }
            unsigned suf2 = s_cum + y;                   // bucket i = 31 - tid
            unsigned long long bm2 = __ballot((tid < 32) && (suf2 >= (unsigned)kl));
            if (tid == 0) {
                int istar = (int)__popcll(bm2) - 1;
                s_thr = (unsigned)(chnk * 32 + istar);
            }
        }
        __syncthreads();
        T = s_thr;
    }
    // ---- vectorized pass filter into LDS staging ----
    const int s0 = sub * chunk;
    const int m = min(chunk, n - s0);
    const int abase = lstart + s0;
    const float* src = obj + (size_t)b * A_TOTAL + abase;
    const int peel0 = (int)(((16u - ((unsigned)(uintptr_t)src & 15u)) & 15u) >> 2);
    const int peel  = (peel0 < m) ? peel0 : m;
    const int nv    = (m - peel) >> 2;
    const float4* s4 = (const float4*)(src + peel);
    const int tail0 = peel + (nv << 2);
#define E1(f, idx) do { unsigned os_ = flipf(f); \
    if ((os_ >> BSHIFT) >= T) { \
        unsigned slot = atomicAdd(&lcnt, 1u); \
        if (slot < CAND_CAP) \
            sbuf[slot] = (((unsigned long long)(~os_)) << 32) | (unsigned)(idx); \
    } } while (0)
#define E4(v, gb) do { E1((v).x, (gb)); E1((v).y, (gb) + 1); \
                       E1((v).z, (gb) + 2); E1((v).w, (gb) + 3); } while (0)
    if (tid < peel) E1(src[tid], abase + tid);
    for (int i = tid; i < nv; i += 512) {
        const int gb0 = abase + peel + (i << 2);
        if (i + 256 < nv) {
            float4 a0 = s4[i], a1 = s4[i + 256];
            E4(a0, gb0);
            E4(a1, gb0 + 1024);
        } else {
            float4 a0 = s4[i];
            E4(a0, gb0);
        }
    }
    for (int i = tail0 + tid; i < m; i += 256) E1(src[i], abase + i);
#undef E4
#undef E1
    __syncthreads();
    unsigned total = lcnt; if (total > CAND_CAP) total = CAND_CAP;
    if (tid == 0) gbase = atomicAdd(&cnt[bl], total);
    __syncthreads();
    const unsigned gb = gbase;
    for (unsigned i = tid; i < total; i += 256) {
        unsigned g = gb + i;
        if (g < CAND_CAP)
            cand[(size_t)bl * CAND_CAP + g] = sbuf[i];
    }
}

// ---------- binary search in LDS: #elements < key ----------
__device__ __forceinline__ int lbound_lds(const unsigned long long* s, int len,
                                          unsigned long long key) {
    int lo = 0, hi = len;
    while (lo < hi) {
        int mid = (lo + hi) >> 1;
        if (s[mid] < key) lo = mid + 1; else hi = mid;
    }
    return lo;
}

// ---------- K3: per-(b,level) bitonic sort + per-image barrier + PARALLEL decode ----------
// 20 blocks x 1024. Sort body verbatim (R7). Then a per-image 5-block spin
// barrier (20 releases total). After the barrier ALL 5 blocks of the image
// decode their own sub-range (sub = l, R7's blockIdx.x mapping).
__global__ __launch_bounds__(1024) void k_sortdec(
        const unsigned long long* __restrict__ cand, const unsigned* __restrict__ cnt,
        unsigned long long* __restrict__ sel,
        const float* __restrict__ deltas, const float* __restrict__ anchors,
        float* __restrict__ boxes_r, float* __restrict__ score_r,
        float* __restrict__ boxes_l, int* __restrict__ valid_l,
        int* __restrict__ rankmap, unsigned* __restrict__ boxmax5,
        unsigned* __restrict__ bar_i) {
    __shared__ __align__(16) char smem[38016];   // sort keys 16K | decode skey 37,928
    __shared__ float wmax[16];
    const int bl = blockIdx.x;
    const int b = bl / NLVL, l = bl - (bl / NLVL) * NLVL;
    const int tid = threadIdx.x;     // 1024

    // ---- sort phase (R7 k_sort body) ----
    {
        unsigned long long* keys = (unsigned long long*)smem;
        int m = (int)cnt[bl];
        if (m > CAND_CAP) m = CAND_CAP;
        for (int i = tid; i < CAND_CAP; i += 1024)
            keys[i] = (i < m) ? cand[(size_t)bl * CAND_CAP + i] : ~0ULL;
        __syncthreads();
        for (int k = 2; k <= CAND_CAP; k <<= 1) {
            for (int j = k >> 1; j > 0; j >>= 1) {
                int i = ((tid / j) * (j << 1)) + (tid % j);
                int p = i + j;
                bool up = ((i & k) == 0);
                unsigned long long a = keys[i], c = keys[p];
                if ((a > c) == up) { keys[i] = c; keys[p] = a; }
                __syncthreads();
            }
        }
        int kl = lvl_k(l);
        for (int q = tid; q < kl; q += 1024)
            sel[(size_t)b * NSEL + l * 1000 + q] = keys[q];
    }
    __syncthreads();   // drain sel stores (vmcnt) before release

    // ---- per-image 5-block spin barrier (all blocks proceed) ----
    if (tid == 0) {
        __threadfence();   // agent release: this block's sel visible
        __hip_atomic_fetch_add(bar_i + b, 1u, __ATOMIC_RELAXED, __HIP_MEMORY_SCOPE_AGENT);
        while (__hip_atomic_load(bar_i + b, __ATOMIC_RELAXED, __HIP_MEMORY_SCOPE_AGENT)
               < (unsigned)NLVL)
            __builtin_amdgcn_s_sleep(2);
        __threadfence();   // agent acquire: all 5 levels' sel visible
    }
    __syncthreads();

    // ---- decode phase (R7 k_decode body; sub = l, full 20-block parallelism) ----
    unsigned long long* skey = (unsigned long long*)smem;
    for (int i = tid; i < NSEL; i += 1024)
        skey[i] = sel[(size_t)b * NSEL + i];
    __syncthreads();
    const int sub = l;
    int p = sub * 1024 + tid;
    bool on = p < NSEL;
    float mx = 0.0f;
    if (on) {
        int l2i = p / 1000;         // p in [4000,4741) -> 4
        int q = p - l2i * 1000;
        unsigned long long key = skey[p];
        unsigned a = (unsigned)(key & 0xFFFFFFFFu);
        unsigned os = ~((unsigned)(key >> 32));
        if (a >= A_TOTAL) a = 0;    // impossible-path safety (MAX padding)
        float score = unflipf(os);
        int r = q;
        for (int l2 = 0; l2 < NLVL; ++l2) {
            if (l2 == l2i) continue;
            r += lbound_lds(skey + l2 * 1000, lvl_k(l2), key);
        }
        const float* dv = deltas + ((size_t)b * A_TOTAL + a) * 4;
        const float* av = anchors + (size_t)a * 4;
        float ax1 = av[0], ay1 = av[1], ax2 = av[2], ay2 = av[3];
        float wa = ax2 - ax1, ha = ay2 - ay1;
        float cxa = ax1 + 0.5f * wa, cya = ay1 + 0.5f * ha;
        float dx = dv[0], dy = dv[1];
        float dw = fminf(dv[2], BBOX_CLIP), dh = fminf(dv[3], BBOX_CLIP);
        float cx = dx * wa + cxa, cy = dy * ha + cya;
        float w = expf(dw) * wa, h = expf(dh) * ha;
        float x1 = cx - 0.5f * w, y1 = cy - 0.5f * h;
        float x2 = cx + 0.5f * w, y2 = cy + 0.5f * h;
        float x1c = fminf(fmaxf(x1, 0.0f), W_IMGF);
        float y1c = fminf(fmaxf(y1, 0.0f), H_IMGF);
        float x2c = fminf(fmaxf(x2, 0.0f), W_IMGF);
        float y2c = fminf(fmaxf(y2, 0.0f), H_IMGF);
        int valid = ((x2c - x1c) >= MIN_SZ) && ((y2c - y1c) >= MIN_SZ);
        mx = fmaxf(fmaxf(x1c, y1c), fmaxf(x2c, y2c));
        size_t rp = (size_t)b * NSEL + r;
        boxes_r[rp * 4 + 0] = x1c; boxes_r[rp * 4 + 1] = y1c;
        boxes_r[rp * 4 + 2] = x2c; boxes_r[rp * 4 + 3] = y2c;
        score_r[rp] = score;
        size_t pp = (size_t)b * NSEL + p;
        boxes_l[pp * 4 + 0] = x1c; boxes_l[pp * 4 + 1] = y1c;
        boxes_l[pp * 4 + 2] = x2c; boxes_l[pp * 4 + 3] = y2c;
        valid_l[pp] = valid;
        rankmap[pp] = r;
    }
    // block max reduction -> private slot (coords >= 0; fmax exact/orderless)
    #pragma unroll
    for (int o = 32; o > 0; o >>= 1)
        mx = fmaxf(mx, __shfl_xor(mx, o));
    if ((tid & 63) == 0) wmax[tid >> 6] = mx;
    __syncthreads();
    if (tid == 0) {
        float m2 = wmax[0];
        #pragma unroll
        for (int i = 1; i < 16; ++i) m2 = fmaxf(m2, wmax[i]);
        boxmax5[b * 5 + sub] = __float_as_uint(m2);
    }
}

// ---------- K4: suppression bitmask (full grid, R7 body; max-of-5 boxmax) ----------
__global__ void k_mask(const float* __restrict__ boxes_l, const unsigned* __restrict__ boxmax5,
                       unsigned long long* __restrict__ mask) {
    int bl = blockIdx.z;
    int b = bl / NLVL, l = bl - b * NLVL;
    int kl = lvl_k(l);
    int w = blockIdx.x, rg = blockIdx.y, tid = threadIdx.x;
    if (rg * 256 >= kl) return;
    float M = __uint_as_float(boxmax5[b * 5 + 0]);
    #pragma unroll
    for (int j = 1; j < 5; ++j) M = fmaxf(M, __uint_as_float(boxmax5[b * 5 + j]));
    M += 1.0f;
    float off = (float)l * M;
    __shared__ float cb[64][5];
    int j0 = w * 64;
    if (tid < 64) {
        int j = j0 + tid;
        if (j < kl) {
            const float* bp = boxes_l + ((size_t)b * NSEL + l * 1000 + j) * 4;
            float x1 = bp[0] + off, y1 = bp[1] + off, x2 = bp[2] + off, y2 = bp[3] + off;
            cb[tid][0] = x1; cb[tid][1] = y1; cb[tid][2] = x2; cb[tid][3] = y2;
            cb[tid][4] = (x2 - x1) * (y2 - y1);
        }
    }
    __syncthreads();
    int i = rg * 256 + tid;
    if (i >= kl) return;
    unsigned long long word = 0;
    if (j0 + 63 > i) {
        const float* bp = boxes_l + ((size_t)b * NSEL + l * 1000 + i) * 4;
        float ix1 = bp[0] + off, iy1 = bp[1] + off, ix2 = bp[2] + off, iy2 = bp[3] + off;
        float ai = (ix2 - ix1) * (iy2 - iy1);
        int jmax = min(64, kl - j0);
        for (int bb = 0; bb < jmax; ++bb) {
            int jj = j0 + bb;
            if (jj <= i) continue;
            float ltx = fmaxf(ix1, cb[bb][0]), lty = fmaxf(iy1, cb[bb][1]);
            float rbx = fminf(ix2, cb[bb][2]), rby = fminf(iy2, cb[bb][3]);
            float ww = fmaxf(rbx - ltx, 0.0f), hh = fmaxf(rby - lty, 0.0f);
            float inter = ww * hh;
            float iou = inter / ((ai + cb[bb][4]) - inter);   // NaN>th == false, matches jnp
            if (iou > NMS_TH) word |= (1ULL << bb);
        }
    }
    mask[((size_t)bl * 1024 + i) * 16 + w] = word;
}

// ---------- K5: resolve (mask slab cooperatively reg-staged into LDS) + output ----------
// 20 blocks x 256. ALL 4 waves copy the full mask slice global->LDS via uint4
// loads 8-deep in flight (2048 outstanding requests of MLP) — replaces R12's
// wave-0-only global_load_lds chain (128 x ~900cyc serialized = the 44us).
// One barrier, then the serial greedy loop runs barrier-free from LDS.
// Resolve logic, scatter, done2 epilogue and output body verbatim from R12.
__global__ __launch_bounds__(256) void k_resout(const int* __restrict__ valid_l,
                                                const int* __restrict__ rankmap,
                                                const unsigned long long* __restrict__ mask,
                                                int* __restrict__ keep_r,
                                                unsigned* __restrict__ done2,
                                                const float* __restrict__ boxes_r,
                                                const float* __restrict__ score_r,
                                                float* __restrict__ out) {
    __shared__ __align__(16) unsigned long long sb[16 * 1024];   // 128 KB: all chunks
    __shared__ int ps[256];
    __shared__ int s_flag;
    const int bl = blockIdx.x;
    const int b = bl / NLVL, l = bl - b * NLVL;
    const int kl = lvl_k(l);
    const int tid = threadIdx.x;     // 256
    const int lane = tid & 63;
    const int base = b * NSEL + l * 1000;
    const int nch = (kl + 63) >> 6;   // 16 or 12
    const char* mbyte = (const char*)(mask + (size_t)bl * 1024 * 16);

    // ---- cooperative reg-staged prefetch: 256 threads, 8-deep MLP ----
    // total uint4s = nch*512 = 8192 (nch=16) or 6144 (nch=12); both % 2048 == 0.
    {
        const uint4* gsrc = (const uint4*)mbyte;
        uint4* ldst = (uint4*)sb;
        const int total = nch * 512;
        for (int i = tid; i < total; i += 2048) {
            uint4 a0 = gsrc[i];
            uint4 a1 = gsrc[i + 256];
            uint4 a2 = gsrc[i + 512];
            uint4 a3 = gsrc[i + 768];
            uint4 a4 = gsrc[i + 1024];
            uint4 a5 = gsrc[i + 1280];
            uint4 a6 = gsrc[i + 1536];
            uint4 a7 = gsrc[i + 1792];
            ldst[i]        = a0; ldst[i + 256]  = a1;
            ldst[i + 512]  = a2; ldst[i + 768]  = a3;
            ldst[i + 1024] = a4; ldst[i + 1280] = a5;
            ldst[i + 1536] = a6; ldst[i + 1792] = a7;
        }
    }
    unsigned long long keep_w = 0;
    if (tid < 64) {
        // keep word per chunk, distributed: lane w (w<16) holds chunk w's bits
        for (int c = 0; c < 16; ++c) {
            int q = c * 64 + lane;
            int vv = (q < kl) ? valid_l[base + q] : 0;
            unsigned long long bm = __ballot(vv);
            if (lane == c) keep_w = bm;
        }
    }
    __syncthreads();                 // entire mask slice staged in LDS

    if (tid < 64) {
        for (int c = 0; c < nch; ++c) {
            unsigned long long* cur = sb + (size_t)c * 1024;
            unsigned long long kw = __shfl(keep_w, c);   // uniform in wave
            if (kw) {
                // diagonal word (word c of this lane's row)
                unsigned long long diag = cur[lane * 16 + c];
                unsigned dlo = (unsigned)diag, dhi = (unsigned)(diag >> 32);
                unsigned long long nz = __ballot(diag != 0ULL);
                unsigned long long rem = kw & nz;
                while (rem) {
                    int rr = __ffsll((long long)rem) - 1;
                    unsigned lo = __builtin_amdgcn_readlane(dlo, rr);
                    unsigned hi = __builtin_amdgcn_readlane(dhi, rr);
                    unsigned long long d = ((unsigned long long)hi << 32) | lo;
                    kw &= ~d;
                    rem &= ~(d | (1ULL << rr));
                }
                // batched cross-chunk suppression: lane w<16 ORs word w of kept rows
                unsigned long long supp = 0;
                if (lane < 16) {
                    #pragma unroll
                    for (int rr = 0; rr < 64; ++rr) {
                        unsigned long long mm = cur[rr * 16 + lane];
                        supp |= (((kw >> rr) & 1ULL) ? mm : 0ULL);
                    }
                }
                if (lane == c) keep_w = kw;
                else if (lane < 16 && lane > c) keep_w &= ~supp;
            }
        }
        // scatter keep bits to global-rank order
        for (int c = 0; c < 16; ++c) {
            unsigned long long kwc = __shfl(keep_w, c);
            int q = c * 64 + lane;
            if (q < kl)
                keep_r[b * NSEL + rankmap[base + q]] = (int)((kwc >> lane) & 1ULL);
        }
    }
    __syncthreads();   // drain keep_r stores before release

    // ---- last-of-image output epilogue (20 releases total) ----
    if (tid == 0) {
        __threadfence();   // agent release: keep_r visible
        unsigned old = __hip_atomic_fetch_add(done2 + b, 1u,
                                              __ATOMIC_ACQ_REL, __HIP_MEMORY_SCOPE_AGENT);
        s_flag = (old == NLVL - 1);
        if (old == NLVL - 1) __threadfence();   // agent acquire
    }
    __syncthreads();
    if (!s_flag) return;

    // verified 256-thread output body (CH=19: 19*256 = 4864 >= 4741)
    float* ob = out + (size_t)b * POST_NMS * 4;
    float* osc = out + (size_t)B_IMGS * POST_NMS * 4 + (size_t)b * POST_NMS;
    for (int p = tid; p < POST_NMS; p += 256) {
        ob[p * 4 + 0] = 0.0f; ob[p * 4 + 1] = 0.0f;
        ob[p * 4 + 2] = 0.0f; ob[p * 4 + 3] = 0.0f;
        osc[p] = NEGV;
    }
    __syncthreads();
    const int CH = 19;
    int basei = tid * CH;
    int c0 = 0;
    #pragma unroll
    for (int k = 0; k < CH; ++k) {
        int rr = basei + k;
        if (rr < NSEL) c0 += keep_r[b * NSEL + rr];
    }
    ps[tid] = c0;
    __syncthreads();
    for (int ofs = 1; ofs < 256; ofs <<= 1) {
        int v = (tid >= ofs) ? ps[tid - ofs] : 0;
        __syncthreads();
        ps[tid] += v;
        __syncthreads();
    }
    int p = ps[tid] - c0;   // exclusive prefix
    #pragma unroll
    for (int k = 0; k < CH; ++k) {
        int rr = basei + k;
        if (rr < NSEL && keep_r[b * NSEL + rr]) {
            if (p < POST_NMS) {
                const float* bp = boxes_r + ((size_t)b * NSEL + rr) * 4;
                ob[p * 4 + 0] = bp[0]; ob[p * 4 + 1] = bp[1];
                ob[p * 4 + 2] = bp[2]; ob[p * 4 + 3] = bp[3];
                osc[p] = score_r[(size_t)b * NSEL + rr];
            }
            ++p;
        }
    }
}

extern "C" void kernel_launch(void* const* d_in, const int* in_sizes, int n_in,
                              void* d_out, int out_size, void* d_ws, size_t ws_size,
                              hipStream_t stream) {
    const float* obj     = (const float*)d_in[0];   // [4, 242991]
    const float* deltas  = (const float*)d_in[1];   // [4, 242991, 4]
    const float* anchors = (const float*)d_in[2];   // [242991, 4]
    float* out = (float*)d_out;                     // [4,1000,4] ++ [4,1000]

    char* ws = (char*)d_ws;
    unsigned*            boxmax5 = (unsigned*)(ws + OFF_BM5);
    unsigned*            cnt     = (unsigned*)(ws + OFF_CNT);
    unsigned*            bar_i   = (unsigned*)(ws + OFF_DI);
    unsigned*            done2   = (unsigned*)(ws + OFF_D2);
    unsigned*            hist_sl = (unsigned*)(ws + OFF_HSL);
    unsigned*            part_sl = (unsigned*)(ws + OFF_PSL);
    unsigned long long*  cand    = (unsigned long long*)(ws + OFF_CAND);
    unsigned long long*  sel     = (unsigned long long*)(ws + OFF_SEL);
    float*               boxes_r = (float*)(ws + OFF_BOXR);
    float*               score_r = (float*)(ws + OFF_SCR);
    float*               boxes_l = (float*)(ws + OFF_BOXL);
    int*                 valid_l = (int*)(ws + OFF_VAL);
    int*                 rankmap = (int*)(ws + OFF_RMAP);
    int*                 keep_r  = (int*)(ws + OFF_KEEP);
    unsigned long long*  maskp   = (unsigned long long*)(ws + OFF_MASK);

    (void)in_sizes; (void)n_in; (void)out_size; (void)ws_size; (void)WS_NEED;

    // No memset: hist/part slices are plain-store overwritten; cnt+bar_i+done2
    // zeroed by k_hist's l4 block (kernel-boundary visibility); boxmax5 is
    // plain-stored by k_sortdec; keep_r fully written before any read.
    k_hist<<<B_IMGS * HBLK_PER_IMG, 512, 0, stream>>>(obj, hist_sl, part_sl, cnt);
    k_compact<<<B_IMGS * CBLK_PER_IMG, 256, 0, stream>>>(obj, hist_sl, part_sl, cnt, cand);
    k_sortdec<<<NBL, 1024, 0, stream>>>(cand, cnt, sel, deltas, anchors,
                                        boxes_r, score_r, boxes_l, valid_l,
                                        rankmap, boxmax5, bar_i);
    k_mask<<<dim3(16, 4, NBL), 256, 0, stream>>>(boxes_l, boxmax5, maskp);
    k_resout<<<NBL, 256, 0, stream>>>(valid_l, rankmap, maskp, keep_r, done2,
                                      boxes_r, score_r, out);
}